// Round 1
// baseline (407.501 us; speedup 1.0000x reference)
//
#include <hip/hip_runtime.h>
#include <hip/hip_bf16.h>

namespace {
constexpr int S    = 2048;
constexpr int HID  = 1024;
constexpr int NKV  = 4;
constexpr int HD   = 64;
constexpr int M    = 2 * S;                 // 4096 rows (B*S)
constexpr int QW   = HID + 2 * NKV * HD;    // 1536: [q(1024) | k(256) | v(256)]
constexpr int KVSZ = HD * HD + HD;          // 4160 floats per (b, kv-head) group
}

// ---------------- f32 SGEMM: 128x128 tile, K-step 16, 256 thr, 8x8/thread ----
// MODE 0: C = X @ [Wq|Wk|Wv]  (N = 1536, B chosen per n-tile)
// MODE 1: C = A  @ W0         (N = 1024)
template <int MODE>
__global__ __launch_bounds__(256) void sgemm_k(
    const float* __restrict__ A, int lda,
    const float* __restrict__ W0, const float* __restrict__ W1,
    const float* __restrict__ W2,
    float* __restrict__ C, int ldc)
{
    __shared__ float As[16][132];   // [k][m], padded
    __shared__ float Bs[16][132];   // [k][n], padded
    const int tid = threadIdx.x;
    const int m0 = blockIdx.x * 128;
    const int n0 = blockIdx.y * 128;

    const float* Bp; int ldb, c0;
    if (MODE == 0) {
        if (n0 < 1024)      { Bp = W0; ldb = 1024; c0 = n0; }
        else if (n0 < 1280) { Bp = W1; ldb = 256;  c0 = n0 - 1024; }
        else                { Bp = W2; ldb = 256;  c0 = n0 - 1280; }
    } else {
        Bp = W0; ldb = 1024; c0 = n0;
    }

    const int tx = tid & 15, ty = tid >> 4;

    float acc[8][8];
#pragma unroll
    for (int i = 0; i < 8; ++i)
#pragma unroll
        for (int j = 0; j < 8; ++j) acc[i][j] = 0.f;

    for (int kt = 0; kt < 1024; kt += 16) {
#pragma unroll
        for (int l = 0; l < 2; ++l) {          // A tile: 128 x 16 (transpose to LDS)
            int idx = tid + l * 256;           // 0..511
            int row = idx >> 2;
            int kc  = (idx & 3) << 2;
            float4 a = *reinterpret_cast<const float4*>(
                &A[(size_t)(m0 + row) * lda + kt + kc]);
            As[kc + 0][row] = a.x; As[kc + 1][row] = a.y;
            As[kc + 2][row] = a.z; As[kc + 3][row] = a.w;
        }
#pragma unroll
        for (int l = 0; l < 2; ++l) {          // B tile: 16 x 128
            int idx = tid + l * 256;
            int row = idx >> 5;
            int col = (idx & 31) << 2;
            *reinterpret_cast<float4*>(&Bs[row][col]) =
                *reinterpret_cast<const float4*>(
                    &Bp[(size_t)(kt + row) * ldb + c0 + col]);
        }
        __syncthreads();
#pragma unroll
        for (int kk = 0; kk < 16; ++kk) {
            float4 a0 = *reinterpret_cast<const float4*>(&As[kk][ty * 8]);
            float4 a1 = *reinterpret_cast<const float4*>(&As[kk][ty * 8 + 4]);
            float4 b0 = *reinterpret_cast<const float4*>(&Bs[kk][tx * 8]);
            float4 b1 = *reinterpret_cast<const float4*>(&Bs[kk][tx * 8 + 4]);
            float av[8] = {a0.x, a0.y, a0.z, a0.w, a1.x, a1.y, a1.z, a1.w};
            float bv[8] = {b0.x, b0.y, b0.z, b0.w, b1.x, b1.y, b1.z, b1.w};
#pragma unroll
            for (int i = 0; i < 8; ++i)
#pragma unroll
                for (int j = 0; j < 8; ++j)
                    acc[i][j] = fmaf(av[i], bv[j], acc[i][j]);
        }
        __syncthreads();
    }
#pragma unroll
    for (int i = 0; i < 8; ++i) {
        int row = m0 + ty * 8 + i;
#pragma unroll
        for (int j = 0; j < 8; j += 4) {
            float4 v = make_float4(acc[i][j], acc[i][j+1], acc[i][j+2], acc[i][j+3]);
            *reinterpret_cast<float4*>(&C[(size_t)row * ldc + n0 + tx * 8 + j]) = v;
        }
    }
}

// -------- RoPE + phi (elu+1) applied in-place to q and k parts of QKV --------
// pair (d, d+32) within each 64-dim head; k rows additionally scaled by mask.
__global__ __launch_bounds__(256) void rope_phi_k(
    float* __restrict__ QKV, const float* __restrict__ Cos,
    const float* __restrict__ Sin, const int* __restrict__ Mask)
{
    int gid = blockIdx.x * 256 + threadIdx.x;     // M * 640 total
    int m   = gid / 640;
    int pid = gid - m * 640;
    int s   = m & (S - 1);
    float* row = QKV + (size_t)m * QW;

    int col, d;
    float maskv = 1.f;
    if (pid < 512) {                 // q: 16 heads * 32 pairs
        int h = pid >> 5; d = pid & 31; col = h * 64 + d;
    } else {                         // k: 4 kv-heads * 32 pairs
        int p = pid - 512;
        int kvh = p >> 5; d = p & 31; col = 1024 + kvh * 64 + d;
        maskv = (float)Mask[m];
    }
    float x0 = row[col], x1 = row[col + 32];
    float c0 = Cos[s * 64 + d], c1 = Cos[s * 64 + d + 32];
    float s0 = Sin[s * 64 + d], s1 = Sin[s * 64 + d + 32];
    float r0 = x0 * c0 - x1 * s0;          // rotate_half: rot[d] = -x[d+32], d<32
    float r1 = x1 * c1 + x0 * s1;          //              rot[d+32] = x[d]
    r0 = r0 > 0.f ? r0 + 1.f : __expf(r0); // elu + 1
    r1 = r1 > 0.f ? r1 + 1.f : __expf(r1);
    row[col]      = r0 * maskv;
    row[col + 32] = r1 * maskv;
}

__global__ __launch_bounds__(256) void zero_k(float* __restrict__ p, int n)
{
    int i = blockIdx.x * 256 + threadIdx.x;
    if (i < n) p[i] = 0.f;
}

// -------- KV = sum_t ktilde (x) v ; Ksum = sum_t ktilde, per (b, kv-head) ----
__global__ __launch_bounds__(256) void kv_accum_k(
    const float* __restrict__ QKV, float* __restrict__ KVS)
{
    const int g   = blockIdx.x;            // b*4 + kvh  (8 groups)
    const int b   = g >> 2, kvh = g & 3;
    const int sc  = blockIdx.y;            // 16 chunks of 128 rows
    const int tid = threadIdx.x;

    __shared__ float ks[16][64];
    __shared__ float vs[16][64];

    float acc[16];
#pragma unroll
    for (int jj = 0; jj < 16; ++jj) acc[jj] = 0.f;
    float ksum = 0.f;

    const int i  = tid >> 2;               // 0..63  (KV row)
    const int j0 = (tid & 3) * 16;         // KV col base
    const int m0 = b * S + sc * 128;

    for (int r0 = 0; r0 < 128; r0 += 16) {
        int row = tid >> 4;                // 0..15
        int cc  = (tid & 15) << 2;
        const float* src = QKV + (size_t)(m0 + r0 + row) * QW + 1024 + kvh * 64 + cc;
        float4 k4 = *reinterpret_cast<const float4*>(src);
        float4 v4 = *reinterpret_cast<const float4*>(src + 256);  // v part (+1280)
        *reinterpret_cast<float4*>(&ks[row][cc]) = k4;
        *reinterpret_cast<float4*>(&vs[row][cc]) = v4;
        __syncthreads();
#pragma unroll
        for (int r = 0; r < 16; ++r) {
            float kv = ks[r][i];
            if (tid < 64) ksum += ks[r][tid];
#pragma unroll
            for (int jj = 0; jj < 16; ++jj)
                acc[jj] = fmaf(kv, vs[r][j0 + jj], acc[jj]);
        }
        __syncthreads();
    }
    float* base = KVS + (size_t)g * KVSZ;
#pragma unroll
    for (int jj = 0; jj < 16; ++jj)
        atomicAdd(&base[i * 64 + j0 + jj], acc[jj]);
    if (tid < 64) atomicAdd(&base[4096 + tid], ksum);
}

// -------- out = (qtilde @ KV) / (qtilde . Ksum), in-place into q columns -----
__global__ __launch_bounds__(256) void attn_out_k(
    float* __restrict__ QKV, const float* __restrict__ KVS)
{
    const int m0  = blockIdx.x * 16;       // 16 rows per block
    const int b   = m0 >> 11;
    const int tid = threadIdx.x;
    const int h   = tid >> 4;              // 0..15
    const int g   = (b << 2) + (h >> 2);
    const int d   = (tid & 15) << 2;

    __shared__ float q[1024];
    const float* KVg  = KVS + (size_t)g * KVSZ;
    const float* Ksum = KVg + 4096;

    for (int r = 0; r < 16; ++r) {
        float* row = QKV + (size_t)(m0 + r) * QW;
        *reinterpret_cast<float4*>(&q[tid * 4]) =
            *reinterpret_cast<const float4*>(&row[tid * 4]);
        __syncthreads();

        float o0 = 0.f, o1 = 0.f, o2 = 0.f, o3 = 0.f, den = 0.f;
        const float* qh = &q[h * 64];
#pragma unroll
        for (int i = 0; i < 64; ++i) {
            float qv  = qh[i];
            float4 kv = *reinterpret_cast<const float4*>(&KVg[i * 64 + d]);
            o0 = fmaf(qv, kv.x, o0);
            o1 = fmaf(qv, kv.y, o1);
            o2 = fmaf(qv, kv.z, o2);
            o3 = fmaf(qv, kv.w, o3);
            den = fmaf(qv, Ksum[i], den);
        }
        float rden = 1.f / fmaxf(den, 1e-6f);
        float4 o = make_float4(o0 * rden, o1 * rden, o2 * rden, o3 * rden);
        __syncthreads();                   // all q reads done before next load
        *reinterpret_cast<float4*>(&row[h * 64 + d]) = o;
    }
}

extern "C" void kernel_launch(void* const* d_in, const int* in_sizes, int n_in,
                              void* d_out, int out_size, void* d_ws, size_t ws_size,
                              hipStream_t stream)
{
    const float* x    = (const float*)d_in[0];
    const float* cosp = (const float*)d_in[1];
    const float* sinp = (const float*)d_in[2];
    const int*   msk  = (const int*)d_in[3];
    const float* Wq   = (const float*)d_in[4];
    const float* Wk   = (const float*)d_in[5];
    const float* Wv   = (const float*)d_in[6];
    const float* Wo   = (const float*)d_in[7];
    float* out = (float*)d_out;

    float* qkv = (float*)d_ws;                   // M x 1536
    float* kvs = qkv + (size_t)M * QW;           // 8 x 4160

    // 1) QKV = X @ [Wq|Wk|Wv]
    sgemm_k<0><<<dim3(M / 128, QW / 128), 256, 0, stream>>>(
        x, 1024, Wq, Wk, Wv, qkv, QW);
    // 2) RoPE + elu+1 in place (k rows masked)
    rope_phi_k<<<(M * 640) / 256, 256, 0, stream>>>(qkv, cosp, sinp, msk);
    // 3) KV / Ksum accumulation
    zero_k<<<(8 * KVSZ + 255) / 256, 256, 0, stream>>>(kvs, 8 * KVSZ);
    kv_accum_k<<<dim3(8, 16), 256, 0, stream>>>(qkv, kvs);
    // 4) normalize: attn rows written into q columns of QKV (in place)
    attn_out_k<<<M / 16, 256, 0, stream>>>(qkv, kvs);
    // 5) out = attn @ Wo
    sgemm_k<1><<<dim3(M / 128, HID / 128), 256, 0, stream>>>(
        qkv, QW, Wo, nullptr, nullptr, out, 1024);
}

// Round 2
// 197.617 us; speedup vs baseline: 2.0621x; 2.0621x over previous
//
#include <hip/hip_runtime.h>
#include <hip/hip_bf16.h>

using u16 = unsigned short;
using u32 = unsigned int;

namespace {
constexpr int S    = 2048;
constexpr int HID  = 1024;
constexpr int HD   = 64;
constexpr int M    = 4096;                 // B*S
constexpr int QW   = 1536;                 // q(1024) | k(256) | v(256)
constexpr int K    = 1024;                 // inner dim of both GEMMs
constexpr int KVSZ = HD * HD + HD;
}

typedef __attribute__((ext_vector_type(8))) short short8;   // 8 bf16 = 4 VGPR
typedef __attribute__((ext_vector_type(4))) float f32x4;

__device__ __forceinline__ u16 f2bf(float f) {
    u32 u = __builtin_bit_cast(u32, f);
    u += 0x7fffu + ((u >> 16) & 1u);       // round-to-nearest-even
    return (u16)(u >> 16);
}
__device__ __forceinline__ float bf2f(u16 h) {
    return __builtin_bit_cast(float, (u32)h << 16);
}

__device__ __forceinline__ void glds16(const u16* g, u16* l) {
    __builtin_amdgcn_global_load_lds(
        (const __attribute__((address_space(1))) u32*)g,
        (__attribute__((address_space(3))) u32*)l, 16, 0, 0);
}

// ---------- bf16x3 MFMA GEMM: C(f32) = (Ah+Al) @ (Bh+Bl)^T-ish ----------
// A*: [M][1024] bf16 row-major (hi/lo).  B*: [N][1024] bf16 row-major =
// W^T pre-transposed (hi/lo).  C: [M][ldc] f32.  Tile 128x128, BK=32,
// 4 waves (2x2), 4x4 16x16x32 frags/wave, 3 MFMAs per frag (hh, hl, lh).
// LDS linear for global_load_lds; k-slot XOR-swizzled on BOTH global-src
// and LDS-read side: slot' = slot ^ ((row>>1)&3)  (rule #21 both-or-neither).
__global__ __launch_bounds__(256, 2) void gemm3_k(
    const u16* __restrict__ Ah, const u16* __restrict__ Al,
    const u16* __restrict__ Bh, const u16* __restrict__ Bl,
    float* __restrict__ C, int ldc)
{
    constexpr int BK = 32;
    __shared__ __align__(16) u16 sAh[128 * BK], sAl[128 * BK];
    __shared__ __align__(16) u16 sBh[128 * BK], sBl[128 * BK];

    const int tid  = threadIdx.x;
    const int lane = tid & 63, w = tid >> 6;
    const int wm = w & 1, wn = w >> 1;             // 2x2 wave grid
    const int m0 = blockIdx.x * 128, n0 = blockIdx.y * 128;
    const int fr = lane & 15, fq = lane >> 4;

    // staging: lane covers (row = lane>>2, slot = lane&3) of a 16-row chunk;
    // fetch the swizzled k-slot so linear LDS ends up swizzle-stored.
    const int str = lane >> 2;
    const int stk = ((lane & 3) ^ ((lane >> 3) & 3)) * 8;

    f32x4 acc[4][4] = {};

    for (int kt = 0; kt < K; kt += BK) {
#pragma unroll
        for (int c = 0; c < 2; ++c) {
            const int r  = w * 32 + c * 16 + str;  // tile row this lane stages
            const int lo = (w * 32 + c * 16) * BK; // wave-uniform LDS base
            glds16(Ah + (size_t)(m0 + r) * K + kt + stk, sAh + lo);
            glds16(Al + (size_t)(m0 + r) * K + kt + stk, sAl + lo);
            glds16(Bh + (size_t)(n0 + r) * K + kt + stk, sBh + lo);
            glds16(Bl + (size_t)(n0 + r) * K + kt + stk, sBl + lo);
        }
        __syncthreads();                           // compiler drains vmcnt

        short8 ah[4], al[4], bh[4], bl[4];
        const int kswz = (fq ^ ((fr >> 1) & 3)) * 8;
#pragma unroll
        for (int i = 0; i < 4; ++i) {
            const int ar = (wm * 64 + i * 16 + fr) * BK + kswz;
            const int br = (wn * 64 + i * 16 + fr) * BK + kswz;
            ah[i] = *(const short8*)(sAh + ar);
            al[i] = *(const short8*)(sAl + ar);
            bh[i] = *(const short8*)(sBh + br);
            bl[i] = *(const short8*)(sBl + br);
        }
#pragma unroll
        for (int i = 0; i < 4; ++i)
#pragma unroll
            for (int j = 0; j < 4; ++j) {
                asm("v_mfma_f32_16x16x32_bf16 %0, %1, %2, %0"
                    : "+v"(acc[i][j]) : "v"(ah[i]), "v"(bh[j]));
                asm("v_mfma_f32_16x16x32_bf16 %0, %1, %2, %0"
                    : "+v"(acc[i][j]) : "v"(ah[i]), "v"(bl[j]));
                asm("v_mfma_f32_16x16x32_bf16 %0, %1, %2, %0"
                    : "+v"(acc[i][j]) : "v"(al[i]), "v"(bh[j]));
            }
        __syncthreads();
    }
    asm volatile("s_nop 7\n\ts_nop 7");            // MFMA->VALU read hazard fence
#pragma unroll
    for (int i = 0; i < 4; ++i)
#pragma unroll
        for (int j = 0; j < 4; ++j) {
            const int row = m0 + wm * 64 + i * 16 + fq * 4;
            const int col = n0 + wn * 64 + j * 16 + fr;
#pragma unroll
            for (int jj = 0; jj < 4; ++jj)
                C[(size_t)(row + jj) * ldc + col] = acc[i][j][jj];
        }
}

// ---------- split x (f32) -> hi/lo bf16, vectorized ----------
__global__ __launch_bounds__(256) void split_x_k(
    const float* __restrict__ X, u16* __restrict__ H, u16* __restrict__ L)
{
    const int i = (blockIdx.x * 256 + threadIdx.x) * 4;
    float4 v = *reinterpret_cast<const float4*>(&X[i]);
    ushort4 h, l;
    h.x = f2bf(v.x); l.x = f2bf(v.x - bf2f(h.x));
    h.y = f2bf(v.y); l.y = f2bf(v.y - bf2f(h.y));
    h.z = f2bf(v.z); l.z = f2bf(v.z - bf2f(h.z));
    h.w = f2bf(v.w); l.w = f2bf(v.w - bf2f(h.w));
    *reinterpret_cast<ushort4*>(&H[i]) = h;
    *reinterpret_cast<ushort4*>(&L[i]) = l;
}

// ---------- transpose + split W [K][N] f32 -> T{h,l} rows [nbase+n][1024] ----
__global__ __launch_bounds__(256) void wsplit_k(
    const float* __restrict__ W, int N,
    u16* __restrict__ Th, u16* __restrict__ Tl, int nbase)
{
    __shared__ float t[32][33];
    const int n0 = blockIdx.x * 32, k0 = blockIdx.y * 32;
    const int tx = threadIdx.x, ty = threadIdx.y;  // 32 x 8
#pragma unroll
    for (int i = 0; i < 4; ++i)
        t[ty + i * 8][tx] = W[(size_t)(k0 + ty + i * 8) * N + n0 + tx];
    __syncthreads();
#pragma unroll
    for (int i = 0; i < 4; ++i) {
        const int n = ty + i * 8;
        float v = t[tx][n];                        // W[k0+tx][n0+n]
        u16 h = f2bf(v);
        size_t o = (size_t)(nbase + n0 + n) * 1024 + k0 + tx;
        Th[o] = h;
        Tl[o] = f2bf(v - bf2f(h));
    }
}

// ---------- RoPE + phi(elu+1) in-place on q,k of QKV; k masked ----------
__global__ __launch_bounds__(256) void rope_phi_k(
    float* __restrict__ QKV, const float* __restrict__ Cos,
    const float* __restrict__ Sin, const int* __restrict__ Mask)
{
    int gid = blockIdx.x * 256 + threadIdx.x;
    int m   = gid / 640;
    int pid = gid - m * 640;
    int s   = m & (S - 1);
    float* row = QKV + (size_t)m * QW;

    int col, d;
    float maskv = 1.f;
    if (pid < 512) {
        int h = pid >> 5; d = pid & 31; col = h * 64 + d;
    } else {
        int p = pid - 512;
        int kvh = p >> 5; d = p & 31; col = 1024 + kvh * 64 + d;
        maskv = (float)Mask[m];
    }
    float x0 = row[col], x1 = row[col + 32];
    float c0 = Cos[s * 64 + d], c1 = Cos[s * 64 + d + 32];
    float s0 = Sin[s * 64 + d], s1 = Sin[s * 64 + d + 32];
    float r0 = x0 * c0 - x1 * s0;
    float r1 = x1 * c1 + x0 * s1;
    r0 = r0 > 0.f ? r0 + 1.f : __expf(r0);
    r1 = r1 > 0.f ? r1 + 1.f : __expf(r1);
    row[col]      = r0 * maskv;
    row[col + 32] = r1 * maskv;
}

__global__ __launch_bounds__(256) void zero_k(float* __restrict__ p, int n)
{
    int i = blockIdx.x * 256 + threadIdx.x;
    if (i < n) p[i] = 0.f;
}

// ---------- KV = sum k~ (x) v ; Ksum = sum k~, per (b, kv-head) ----------
__global__ __launch_bounds__(256) void kv_accum_k(
    const float* __restrict__ QKV, float* __restrict__ KVS)
{
    const int g   = blockIdx.x;
    const int b   = g >> 2, kvh = g & 3;
    const int sc  = blockIdx.y;
    const int tid = threadIdx.x;

    __shared__ float ks[16][64];
    __shared__ float vs[16][64];

    float acc[16];
#pragma unroll
    for (int jj = 0; jj < 16; ++jj) acc[jj] = 0.f;
    float ksum = 0.f;

    const int i  = tid >> 2;
    const int j0 = (tid & 3) * 16;
    const int m0 = b * S + sc * 128;

    for (int r0 = 0; r0 < 128; r0 += 16) {
        int row = tid >> 4;
        int cc  = (tid & 15) << 2;
        const float* src = QKV + (size_t)(m0 + r0 + row) * QW + 1024 + kvh * 64 + cc;
        float4 k4 = *reinterpret_cast<const float4*>(src);
        float4 v4 = *reinterpret_cast<const float4*>(src + 256);
        *reinterpret_cast<float4*>(&ks[row][cc]) = k4;
        *reinterpret_cast<float4*>(&vs[row][cc]) = v4;
        __syncthreads();
#pragma unroll
        for (int r = 0; r < 16; ++r) {
            float kv = ks[r][i];
            if (tid < 64) ksum += ks[r][tid];
#pragma unroll
            for (int jj = 0; jj < 16; ++jj)
                acc[jj] = fmaf(kv, vs[r][j0 + jj], acc[jj]);
        }
        __syncthreads();
    }
    float* base = KVS + (size_t)g * KVSZ;
#pragma unroll
    for (int jj = 0; jj < 16; ++jj)
        atomicAdd(&base[i * 64 + j0 + jj], acc[jj]);
    if (tid < 64) atomicAdd(&base[4096 + tid], ksum);
}

// ---- out = (q~ @ KV) / (q~ . Ksum) -> split bf16 hi/lo dense [M][1024] ----
__global__ __launch_bounds__(256) void attn_out_k(
    const float* __restrict__ QKV, const float* __restrict__ KVS,
    u16* __restrict__ Oh, u16* __restrict__ Ol)
{
    const int m0  = blockIdx.x * 16;
    const int b   = m0 >> 11;
    const int tid = threadIdx.x;
    const int h   = tid >> 4;
    const int g   = (b << 2) + (h >> 2);
    const int d   = (tid & 15) << 2;

    __shared__ float q[1024];
    const float* KVg  = KVS + (size_t)g * KVSZ;
    const float* Ksum = KVg + 4096;

    for (int r = 0; r < 16; ++r) {
        const float* row = QKV + (size_t)(m0 + r) * QW;
        *reinterpret_cast<float4*>(&q[tid * 4]) =
            *reinterpret_cast<const float4*>(&row[tid * 4]);
        __syncthreads();

        float o0 = 0.f, o1 = 0.f, o2 = 0.f, o3 = 0.f, den = 0.f;
        const float* qh = &q[h * 64];
#pragma unroll
        for (int i = 0; i < 64; ++i) {
            float qv  = qh[i];
            float4 kv = *reinterpret_cast<const float4*>(&KVg[i * 64 + d]);
            o0 = fmaf(qv, kv.x, o0);
            o1 = fmaf(qv, kv.y, o1);
            o2 = fmaf(qv, kv.z, o2);
            o3 = fmaf(qv, kv.w, o3);
            den = fmaf(qv, Ksum[i], den);
        }
        float rden = 1.f / fmaxf(den, 1e-6f);
        float4 o = make_float4(o0 * rden, o1 * rden, o2 * rden, o3 * rden);
        __syncthreads();

        ushort4 hv, lv;
        hv.x = f2bf(o.x); lv.x = f2bf(o.x - bf2f(hv.x));
        hv.y = f2bf(o.y); lv.y = f2bf(o.y - bf2f(hv.y));
        hv.z = f2bf(o.z); lv.z = f2bf(o.z - bf2f(hv.z));
        hv.w = f2bf(o.w); lv.w = f2bf(o.w - bf2f(hv.w));
        size_t off = (size_t)(m0 + r) * 1024 + h * 64 + d;
        *reinterpret_cast<ushort4*>(&Oh[off]) = hv;
        *reinterpret_cast<ushort4*>(&Ol[off]) = lv;
    }
}

extern "C" void kernel_launch(void* const* d_in, const int* in_sizes, int n_in,
                              void* d_out, int out_size, void* d_ws, size_t ws_size,
                              hipStream_t stream)
{
    const float* x    = (const float*)d_in[0];
    const float* cosp = (const float*)d_in[1];
    const float* sinp = (const float*)d_in[2];
    const int*   msk  = (const int*)d_in[3];
    const float* Wq   = (const float*)d_in[4];
    const float* Wk   = (const float*)d_in[5];
    const float* Wv   = (const float*)d_in[6];
    const float* Wo   = (const float*)d_in[7];
    float* out = (float*)d_out;

    // workspace layout (~52.6 MB)
    float* qkv = (float*)d_ws;                       // [4096][1536] f32
    float* kvs = qkv + (size_t)M * QW;               // 8 * 4160
    u16* xh  = (u16*)(kvs + 8 * KVSZ);               // [4096][1024] bf16 hi
    u16* xl  = xh  + (size_t)M * K;                  // lo
    u16* bth = xl  + (size_t)M * K;                  // [1536][1024] = [Wq|Wk|Wv]^T hi
    u16* btl = bth + (size_t)1536 * K;
    u16* woh = btl + (size_t)1536 * K;               // [1024][1024] = Wo^T hi
    u16* wol = woh + (size_t)K * K;
    // attn output aliases x's split buffers (x consumed by GEMM0 by then)
    u16* a2h = xh; u16* a2l = xl;

    // 1) precision-split x and transposed weights
    split_x_k<<<(M * K) / 1024, 256, 0, stream>>>(x, xh, xl);
    dim3 wb(32, 8);
    wsplit_k<<<dim3(32, 32), wb, 0, stream>>>(Wq, 1024, bth, btl, 0);
    wsplit_k<<<dim3(8, 32),  wb, 0, stream>>>(Wk, 256,  bth, btl, 1024);
    wsplit_k<<<dim3(8, 32),  wb, 0, stream>>>(Wv, 256,  bth, btl, 1280);
    wsplit_k<<<dim3(32, 32), wb, 0, stream>>>(Wo, 1024, woh, wol, 0);

    // 2) QKV = x @ [Wq|Wk|Wv]   (bf16x3 MFMA)
    gemm3_k<<<dim3(M / 128, QW / 128), 256, 0, stream>>>(
        xh, xl, bth, btl, qkv, QW);

    // 3) RoPE + elu+1 (k masked)
    rope_phi_k<<<(M * 640) / 256, 256, 0, stream>>>(qkv, cosp, sinp, msk);

    // 4) KV / Ksum accumulation
    zero_k<<<(8 * KVSZ + 255) / 256, 256, 0, stream>>>(kvs, 8 * KVSZ);
    kv_accum_k<<<dim3(8, 16), 256, 0, stream>>>(qkv, kvs);

    // 5) attn rows -> dense bf16 hi/lo
    attn_out_k<<<M / 16, 256, 0, stream>>>(qkv, kvs, a2h, a2l);

    // 6) out = attn @ Wo   (bf16x3 MFMA)
    gemm3_k<<<dim3(M / 128, HID / 128), 256, 0, stream>>>(
        a2h, a2l, woh, wol, out, HID);
}

// Round 3
// 137.233 us; speedup vs baseline: 2.9694x; 1.4400x over previous
//
#include <hip/hip_runtime.h>
#include <hip/hip_bf16.h>

using u16 = unsigned short;
using u32 = unsigned int;

namespace {
constexpr int S   = 2048;
constexpr int HID = 1024;
constexpr int M   = 4096;                  // B*S
constexpr int QW  = 1536;                  // q(1024) | k(256) | v(256)
constexpr int K   = 1024;                  // inner dim of both big GEMMs
}

typedef __attribute__((ext_vector_type(8))) short short8;   // 8 bf16 = 4 VGPR
typedef __attribute__((ext_vector_type(4))) float f32x4;

__device__ __forceinline__ u16 f2bf(float f) {
    u32 u = __builtin_bit_cast(u32, f);
    u += 0x7fffu + ((u >> 16) & 1u);       // RNE
    return (u16)(u >> 16);
}
__device__ __forceinline__ float bf2f(u16 h) {
    return __builtin_bit_cast(float, (u32)h << 16);
}
__device__ __forceinline__ float phi(float x) {   // elu(x)+1
    return x > 0.f ? x + 1.f : __expf(x);
}
__device__ __forceinline__ void glds16(const u16* g, u16* l) {
    __builtin_amdgcn_global_load_lds(
        (const __attribute__((address_space(1))) u32*)g,
        (__attribute__((address_space(3))) u32*)l, 16, 0, 0);
}

// ---------- bf16x3 MFMA GEMM, 128x128 tile, BK=32 ----------
// MODE 0: fused RoPE+phi epilogue (QKV projection; k-cols masked, v passthrough)
// MODE 1: plain C write. z-grid offsets rows by zAr/zBr/zCr per blockIdx.z.
template <int MODE>
__global__ __launch_bounds__(256, 2) void gemm3_k(
    const u16* __restrict__ Ah, const u16* __restrict__ Al,
    const u16* __restrict__ Bh, const u16* __restrict__ Bl,
    float* __restrict__ C, int ldc, int zAr, int zBr, int zCr,
    const float* __restrict__ Cos, const float* __restrict__ Sin,
    const int* __restrict__ Mask)
{
    constexpr int BK = 32;
    __shared__ __align__(16) u16 sAh[128 * BK], sAl[128 * BK];
    __shared__ __align__(16) u16 sBh[128 * BK], sBl[128 * BK];

    Ah += (size_t)blockIdx.z * zAr * K;  Al += (size_t)blockIdx.z * zAr * K;
    Bh += (size_t)blockIdx.z * zBr * K;  Bl += (size_t)blockIdx.z * zBr * K;
    C  += (size_t)blockIdx.z * zCr * ldc;

    const int tid  = threadIdx.x;
    const int lane = tid & 63, w = tid >> 6;
    const int wm = w & 1, wn = w >> 1;
    const int m0 = blockIdx.x * 128, n0 = blockIdx.y * 128;
    const int fr = lane & 15, fq = lane >> 4;

    const int str = lane >> 2;
    const int stk = ((lane & 3) ^ ((lane >> 3) & 3)) * 8;

    f32x4 acc[4][4] = {};

    for (int kt = 0; kt < K; kt += BK) {
#pragma unroll
        for (int c = 0; c < 2; ++c) {
            const int r  = w * 32 + c * 16 + str;
            const int lo = (w * 32 + c * 16) * BK;
            glds16(Ah + (size_t)(m0 + r) * K + kt + stk, sAh + lo);
            glds16(Al + (size_t)(m0 + r) * K + kt + stk, sAl + lo);
            glds16(Bh + (size_t)(n0 + r) * K + kt + stk, sBh + lo);
            glds16(Bl + (size_t)(n0 + r) * K + kt + stk, sBl + lo);
        }
        __syncthreads();

        short8 ah[4], al[4], bh[4], bl[4];
        const int kswz = (fq ^ ((fr >> 1) & 3)) * 8;
#pragma unroll
        for (int i = 0; i < 4; ++i) {
            const int ar = (wm * 64 + i * 16 + fr) * BK + kswz;
            const int br = (wn * 64 + i * 16 + fr) * BK + kswz;
            ah[i] = *(const short8*)(sAh + ar);
            al[i] = *(const short8*)(sAl + ar);
            bh[i] = *(const short8*)(sBh + br);
            bl[i] = *(const short8*)(sBl + br);
        }
#pragma unroll
        for (int i = 0; i < 4; ++i)
#pragma unroll
            for (int j = 0; j < 4; ++j) {
                asm("v_mfma_f32_16x16x32_bf16 %0, %1, %2, %0"
                    : "+v"(acc[i][j]) : "v"(ah[i]), "v"(bh[j]));
                asm("v_mfma_f32_16x16x32_bf16 %0, %1, %2, %0"
                    : "+v"(acc[i][j]) : "v"(ah[i]), "v"(bl[j]));
                asm("v_mfma_f32_16x16x32_bf16 %0, %1, %2, %0"
                    : "+v"(acc[i][j]) : "v"(al[i]), "v"(bh[j]));
            }
        __syncthreads();
    }
    asm volatile("s_nop 7\n\ts_nop 7");

    const bool isV = (MODE == 0) && (n0 >= 1280);
    const bool isK = (MODE == 0) && (n0 >= 1024) && (n0 < 1280);
#pragma unroll
    for (int i = 0; i < 4; ++i)
#pragma unroll
        for (int jj = 0; jj < 4; ++jj) {
            const int row = m0 + wm * 64 + i * 16 + fq * 4 + jj;
            float v0 = acc[i][0][jj], v1 = acc[i][1][jj];
            float v2 = acc[i][2][jj], v3 = acc[i][3][jj];
            if (MODE == 0 && !isV) {
                const int sb = (row & (S - 1)) * 64;
                // pairs (d, d+32): (v0@fr, v2@fr+32), (v1@16+fr, v3@48+fr)
                float r0 = v0 * Cos[sb + fr]      - v2 * Sin[sb + fr];
                float r2 = v2 * Cos[sb + fr + 32] + v0 * Sin[sb + fr + 32];
                float r1 = v1 * Cos[sb + fr + 16] - v3 * Sin[sb + fr + 16];
                float r3 = v3 * Cos[sb + fr + 48] + v1 * Sin[sb + fr + 48];
                r0 = phi(r0); r1 = phi(r1); r2 = phi(r2); r3 = phi(r3);
                if (isK) {
                    float mv = (float)Mask[row];
                    r0 *= mv; r1 *= mv; r2 *= mv; r3 *= mv;
                }
                v0 = r0; v1 = r1; v2 = r2; v3 = r3;
            }
            float* cr = &C[(size_t)row * ldc + n0 + wn * 64 + fr];
            cr[0]  = v0; cr[16] = v1; cr[32] = v2; cr[48] = v3;
        }
}

// ---------- split x (f32) -> hi/lo bf16 ----------
__global__ __launch_bounds__(256) void split_x_k(
    const float* __restrict__ X, u16* __restrict__ H, u16* __restrict__ L)
{
    const int i = (blockIdx.x * 256 + threadIdx.x) * 4;
    float4 v = *reinterpret_cast<const float4*>(&X[i]);
    ushort4 h, l;
    h.x = f2bf(v.x); l.x = f2bf(v.x - bf2f(h.x));
    h.y = f2bf(v.y); l.y = f2bf(v.y - bf2f(h.y));
    h.z = f2bf(v.z); l.z = f2bf(v.z - bf2f(h.z));
    h.w = f2bf(v.w); l.w = f2bf(v.w - bf2f(h.w));
    *reinterpret_cast<ushort4*>(&H[i]) = h;
    *reinterpret_cast<ushort4*>(&L[i]) = l;
}

// ---------- transpose + split W [K][N] -> rows [nbase+n][1024] hi/lo ----------
__global__ __launch_bounds__(256) void wsplit_k(
    const float* __restrict__ W, int N,
    u16* __restrict__ Th, u16* __restrict__ Tl, int nbase)
{
    __shared__ float t[32][33];
    const int n0 = blockIdx.x * 32, k0 = blockIdx.y * 32;
    const int tx = threadIdx.x, ty = threadIdx.y;   // 32 x 8
#pragma unroll
    for (int i = 0; i < 4; ++i)
        t[ty + i * 8][tx] = W[(size_t)(k0 + ty + i * 8) * N + n0 + tx];
    __syncthreads();
#pragma unroll
    for (int i = 0; i < 4; ++i) {
        const int n = ty + i * 8;
        float v = t[tx][n];
        u16 h = f2bf(v);
        size_t o = (size_t)(nbase + n0 + n) * 1024 + k0 + tx;
        Th[o] = h;
        Tl[o] = f2bf(v - bf2f(h));
    }
}

// ---------- stage1: per (group, 64-row chunk) partial KV + Ksum, no atomics --
__global__ __launch_bounds__(256) void kv_stage1_k(
    const float* __restrict__ QKV, float* __restrict__ part)
{
    const int g  = blockIdx.x;             // b*4 + kvh
    const int ch = blockIdx.y;             // 32 chunks of 64 rows
    const int b  = g >> 2, kvh = g & 3;
    const int tid = threadIdx.x;

    __shared__ float ks[64][64];
    __shared__ float vs[64][64];
    const int m0 = b * S + ch * 64;
#pragma unroll
    for (int l = 0; l < 4; ++l) {
        int idx = tid + l * 256;           // 0..1023
        int r = idx >> 4, q4 = (idx & 15) * 4;
        const float* src = QKV + (size_t)(m0 + r) * QW + 1024 + kvh * 64;
        *reinterpret_cast<float4*>(&ks[r][q4]) = *reinterpret_cast<const float4*>(src + q4);
        *reinterpret_cast<float4*>(&vs[r][q4]) = *reinterpret_cast<const float4*>(src + 256 + q4);
    }
    __syncthreads();

    const int i = tid >> 2, j0 = (tid & 3) * 16;
    float4 a0 = {0,0,0,0}, a1 = {0,0,0,0}, a2 = {0,0,0,0}, a3 = {0,0,0,0};
#pragma unroll 8
    for (int r = 0; r < 64; ++r) {
        float kv = ks[r][i];
        float4 w0 = *reinterpret_cast<const float4*>(&vs[r][j0]);
        float4 w1 = *reinterpret_cast<const float4*>(&vs[r][j0 + 4]);
        float4 w2 = *reinterpret_cast<const float4*>(&vs[r][j0 + 8]);
        float4 w3 = *reinterpret_cast<const float4*>(&vs[r][j0 + 12]);
        a0.x = fmaf(kv, w0.x, a0.x); a0.y = fmaf(kv, w0.y, a0.y);
        a0.z = fmaf(kv, w0.z, a0.z); a0.w = fmaf(kv, w0.w, a0.w);
        a1.x = fmaf(kv, w1.x, a1.x); a1.y = fmaf(kv, w1.y, a1.y);
        a1.z = fmaf(kv, w1.z, a1.z); a1.w = fmaf(kv, w1.w, a1.w);
        a2.x = fmaf(kv, w2.x, a2.x); a2.y = fmaf(kv, w2.y, a2.y);
        a2.z = fmaf(kv, w2.z, a2.z); a2.w = fmaf(kv, w2.w, a2.w);
        a3.x = fmaf(kv, w3.x, a3.x); a3.y = fmaf(kv, w3.y, a3.y);
        a3.z = fmaf(kv, w3.z, a3.z); a3.w = fmaf(kv, w3.w, a3.w);
    }
    float* dst = part + ((size_t)g * 32 + ch) * 4160;
    float* d0 = dst + i * 64 + j0;
    *reinterpret_cast<float4*>(d0)      = a0;
    *reinterpret_cast<float4*>(d0 + 4)  = a1;
    *reinterpret_cast<float4*>(d0 + 8)  = a2;
    *reinterpret_cast<float4*>(d0 + 12) = a3;
    if (tid < 64) {
        float ksum = 0.f;
#pragma unroll 8
        for (int r = 0; r < 64; ++r) ksum += ks[r][tid];
        dst[4096 + tid] = ksum;
    }
}

// ---------- stage2: sum 32 partials; KV -> bf16 hi/lo, Ksum -> f32 ----------
__global__ __launch_bounds__(256) void kv_reduce_k(
    const float* __restrict__ part, u16* __restrict__ KVh,
    u16* __restrict__ KVl, float* __restrict__ Ksumf)
{
    const int g = blockIdx.x;
    const int e = blockIdx.y * 256 + threadIdx.x;
    if (e >= 4160) return;
    const float* p = part + (size_t)g * 32 * 4160 + e;
    float s = 0.f;
#pragma unroll 8
    for (int c = 0; c < 32; ++c) s += p[(size_t)c * 4160];
    if (e < 4096) {
        u16 h = f2bf(s);
        KVh[g * 4096 + e] = h;
        KVl[g * 4096 + e] = f2bf(s - bf2f(h));
    } else {
        Ksumf[g * 64 + (e - 4096)] = s;
    }
}

// ---------- KWT[b][o][h*64+i] = sum_j KV[i][j] * Wo[h*64+j][o], bf16x3 -------
// A = Wo^T rows (o, k-slice h*64..+64), B = KV rows (i, j-contig). Tile 128x64.
__global__ __launch_bounds__(256, 2) void kw_gemm_k(
    const u16* __restrict__ Woh, const u16* __restrict__ Wol,
    const u16* __restrict__ KVh, const u16* __restrict__ KVl,
    u16* __restrict__ KWh, u16* __restrict__ KWl)
{
    __shared__ __align__(16) u16 sAh[128 * 64], sAl[128 * 64];
    __shared__ __align__(16) u16 sBh[64 * 64],  sBl[64 * 64];

    const int tid = threadIdx.x, lane = tid & 63, w = tid >> 6;
    const int o0 = blockIdx.x * 128;
    const int gh = blockIdx.y, b = gh >> 4, h = gh & 15, g = b * 4 + (h >> 2);
    const int fr = lane & 15, fq = lane >> 4;
    const int srow = lane >> 3, sslot = lane & 7;
    const int sswz = (sslot ^ srow) * 8;

#pragma unroll
    for (int c = 0; c < 4; ++c) {                      // A: 128 rows
        const int rb = w * 32 + c * 8;
        const size_t go = (size_t)(o0 + rb + srow) * 1024 + h * 64 + sswz;
        glds16(Woh + go, sAh + rb * 64);
        glds16(Wol + go, sAl + rb * 64);
    }
#pragma unroll
    for (int c = 0; c < 2; ++c) {                      // B: 64 rows
        const int rb = w * 16 + c * 8;
        const size_t go = (size_t)g * 4096 + (rb + srow) * 64 + sswz;
        glds16(KVh + go, sBh + rb * 64);
        glds16(KVl + go, sBl + rb * 64);
    }
    __syncthreads();

    f32x4 acc[2][4] = {};
#pragma unroll
    for (int kk = 0; kk < 2; ++kk) {
        short8 a_h[2], a_l[2], b_h[4], b_l[4];
#pragma unroll
        for (int i = 0; i < 2; ++i) {
            const int row = w * 32 + i * 16 + fr;
            const int off = row * 64 + ((kk * 4 + fq) ^ (fr & 7)) * 8;
            a_h[i] = *(const short8*)(sAh + off);
            a_l[i] = *(const short8*)(sAl + off);
        }
#pragma unroll
        for (int j = 0; j < 4; ++j) {
            const int row = j * 16 + fr;
            const int off = row * 64 + ((kk * 4 + fq) ^ (fr & 7)) * 8;
            b_h[j] = *(const short8*)(sBh + off);
            b_l[j] = *(const short8*)(sBl + off);
        }
#pragma unroll
        for (int i = 0; i < 2; ++i)
#pragma unroll
            for (int j = 0; j < 4; ++j) {
                asm("v_mfma_f32_16x16x32_bf16 %0, %1, %2, %0"
                    : "+v"(acc[i][j]) : "v"(a_h[i]), "v"(b_h[j]));
                asm("v_mfma_f32_16x16x32_bf16 %0, %1, %2, %0"
                    : "+v"(acc[i][j]) : "v"(a_h[i]), "v"(b_l[j]));
                asm("v_mfma_f32_16x16x32_bf16 %0, %1, %2, %0"
                    : "+v"(acc[i][j]) : "v"(a_l[i]), "v"(b_h[j]));
            }
    }
    asm volatile("s_nop 7\n\ts_nop 7");
#pragma unroll
    for (int i = 0; i < 2; ++i)
#pragma unroll
        for (int j = 0; j < 4; ++j)
#pragma unroll
            for (int jj = 0; jj < 4; ++jj) {
                const int row = o0 + w * 32 + i * 16 + fq * 4 + jj;   // o
                const int col = j * 16 + fr;                          // i of KV
                float v = acc[i][j][jj];
                u16 hh = f2bf(v);
                size_t off = ((size_t)b * 1024 + row) * 1024 + h * 64 + col;
                KWh[off] = hh;
                KWl[off] = f2bf(v - bf2f(hh));
            }
}

// ---------- q_hat = q~ / max(q~.Ksum, 1e-6) -> bf16 hi/lo [M][1024] ----------
__global__ __launch_bounds__(256) void den_split_k(
    const float* __restrict__ QKV, const float* __restrict__ Ksumf,
    u16* __restrict__ Qh, u16* __restrict__ Ql)
{
    const int t = blockIdx.x * 256 + threadIdx.x;   // (m, h)
    const int m = t >> 4, h = t & 15;
    const int g = (m >> 11) * 4 + (h >> 2);
    const float* q  = QKV + (size_t)m * QW + h * 64;
    const float* Ks = Ksumf + g * 64;

    float4 qv[16];
    float den = 0.f;
#pragma unroll
    for (int c = 0; c < 16; ++c) {
        qv[c] = *reinterpret_cast<const float4*>(&q[c * 4]);
        den = fmaf(qv[c].x, Ks[c * 4 + 0], den);
        den = fmaf(qv[c].y, Ks[c * 4 + 1], den);
        den = fmaf(qv[c].z, Ks[c * 4 + 2], den);
        den = fmaf(qv[c].w, Ks[c * 4 + 3], den);
    }
    const float rd = 1.f / fmaxf(den, 1e-6f);
    const size_t o = (size_t)m * 1024 + h * 64;
#pragma unroll
    for (int c = 0; c < 16; ++c) {
        float x0 = qv[c].x * rd, x1 = qv[c].y * rd;
        float x2 = qv[c].z * rd, x3 = qv[c].w * rd;
        ushort4 hh, ll;
        hh.x = f2bf(x0); ll.x = f2bf(x0 - bf2f(hh.x));
        hh.y = f2bf(x1); ll.y = f2bf(x1 - bf2f(hh.y));
        hh.z = f2bf(x2); ll.z = f2bf(x2 - bf2f(hh.z));
        hh.w = f2bf(x3); ll.w = f2bf(x3 - bf2f(hh.w));
        *reinterpret_cast<ushort4*>(&Qh[o + c * 4]) = hh;
        *reinterpret_cast<ushort4*>(&Ql[o + c * 4]) = ll;
    }
}

extern "C" void kernel_launch(void* const* d_in, const int* in_sizes, int n_in,
                              void* d_out, int out_size, void* d_ws, size_t ws_size,
                              hipStream_t stream)
{
    const float* x    = (const float*)d_in[0];
    const float* cosp = (const float*)d_in[1];
    const float* sinp = (const float*)d_in[2];
    const int*   msk  = (const int*)d_in[3];
    const float* Wq   = (const float*)d_in[4];
    const float* Wk   = (const float*)d_in[5];
    const float* Wv   = (const float*)d_in[6];
    const float* Wo   = (const float*)d_in[7];
    float* out = (float*)d_out;

    // ---- workspace layout (~65 MB) ----
    float* qkv   = (float*)d_ws;                      // [4096][1536]
    float* part  = qkv + (size_t)M * QW;              // [8][32][4160]
    float* ksumf = part + (size_t)8 * 32 * 4160;      // [8][64]
    u16* xh  = (u16*)(ksumf + 512);                   // [4096][1024]
    u16* xl  = xh  + (size_t)M * K;
    u16* bth = xl  + (size_t)M * K;                   // [1536][1024]
    u16* btl = bth + (size_t)1536 * K;
    u16* woh = btl + (size_t)1536 * K;                // [1024][1024] Wo^T
    u16* wol = woh + (size_t)K * K;
    u16* kvh = wol + (size_t)K * K;                   // [8][4096]
    u16* kvl = kvh + 8 * 4096;
    u16* kwh = kvl + 8 * 4096;                        // [2][1024][1024]
    u16* kwl = kwh + (size_t)2 * K * K;
    u16* qh  = xh;                                    // alias (x consumed)
    u16* ql  = xl;

    // 1) precision splits
    split_x_k<<<(M * K) / 1024, 256, 0, stream>>>(x, xh, xl);
    dim3 wb(32, 8);
    wsplit_k<<<dim3(32, 32), wb, 0, stream>>>(Wq, 1024, bth, btl, 0);
    wsplit_k<<<dim3(8, 32),  wb, 0, stream>>>(Wk, 256,  bth, btl, 1024);
    wsplit_k<<<dim3(8, 32),  wb, 0, stream>>>(Wv, 256,  bth, btl, 1280);
    wsplit_k<<<dim3(32, 32), wb, 0, stream>>>(Wo, 1024, woh, wol, 0);

    // 2) QKV = x @ [Wq|Wk|Wv] with fused RoPE + phi (+mask on k)
    gemm3_k<0><<<dim3(M / 128, QW / 128, 1), 256, 0, stream>>>(
        xh, xl, bth, btl, qkv, QW, 0, 0, 0, cosp, sinp, msk);

    // 3) KV & Ksum (atomic-free two-stage)
    kv_stage1_k<<<dim3(8, 32), 256, 0, stream>>>(qkv, part);
    kv_reduce_k<<<dim3(8, 17), 256, 0, stream>>>(part, kvh, kvl, ksumf);

    // 4) KWT[b] = per-head KV @ Wo slices (bf16x3 MFMA)
    kw_gemm_k<<<dim3(8, 32), 256, 0, stream>>>(woh, wol, kvh, kvl, kwh, kwl);

    // 5) q_hat = q~ / den -> bf16 hi/lo
    den_split_k<<<(M * 16) / 256, 256, 0, stream>>>(qkv, ksumf, qh, ql);

    // 6) out_b = q_hat_b @ KWT_b^T
    gemm3_k<1><<<dim3(2048 / 128, HID / 128, 2), 256, 0, stream>>>(
        qh, ql, kwh, kwl, out, HID, 2048, 1024, 2048,
        nullptr, nullptr, nullptr);
}

// Round 6
// 136.640 us; speedup vs baseline: 2.9823x; 1.0043x over previous
//
#include <hip/hip_runtime.h>
#include <hip/hip_bf16.h>

using u16 = unsigned short;
using u32 = unsigned int;

namespace {
constexpr int S   = 2048;
constexpr int HID = 1024;
constexpr int M   = 4096;                  // B*S
constexpr int QW  = 1536;                  // q(1024) | k(256) | v(256)
constexpr int K   = 1024;                  // inner dim of both big GEMMs
}

typedef __attribute__((ext_vector_type(8))) short short8;   // 8 bf16 = 4 VGPR
typedef __attribute__((ext_vector_type(4))) float f32x4;

__device__ __forceinline__ u16 f2bf(float f) {
    u32 u = __builtin_bit_cast(u32, f);
    u += 0x7fffu + ((u >> 16) & 1u);       // RNE
    return (u16)(u >> 16);
}
__device__ __forceinline__ float bf2f(u16 h) {
    return __builtin_bit_cast(float, (u32)h << 16);
}
__device__ __forceinline__ float phi(float x) {   // elu(x)+1
    return x > 0.f ? x + 1.f : __expf(x);
}
__device__ __forceinline__ void glds16(const u16* g, u16* l) {
    __builtin_amdgcn_global_load_lds(
        (const __attribute__((address_space(1))) u32*)g,
        (__attribute__((address_space(3))) u32*)l, 16, 0, 0);
}

// ---------- bf16x3 MFMA GEMM: byte-identical to round 3 (PASSING) ----------
// MODE 0: fused RoPE+phi epilogue (QKV projection; k-cols masked, v pass).
// MODE 1: plain C write. z-grid offsets rows by zAr/zBr/zCr per blockIdx.z.
template <int MODE>
__global__ __launch_bounds__(256, 2) void gemm3_k(
    const u16* __restrict__ Ah, const u16* __restrict__ Al,
    const u16* __restrict__ Bh, const u16* __restrict__ Bl,
    float* __restrict__ C, int ldc, int zAr, int zBr, int zCr,
    const float* __restrict__ Cos, const float* __restrict__ Sin,
    const int* __restrict__ Mask)
{
    constexpr int BK = 32;
    __shared__ __align__(16) u16 sAh[128 * BK], sAl[128 * BK];
    __shared__ __align__(16) u16 sBh[128 * BK], sBl[128 * BK];

    Ah += (size_t)blockIdx.z * zAr * K;  Al += (size_t)blockIdx.z * zAr * K;
    Bh += (size_t)blockIdx.z * zBr * K;  Bl += (size_t)blockIdx.z * zBr * K;
    C  += (size_t)blockIdx.z * zCr * ldc;

    const int tid  = threadIdx.x;
    const int lane = tid & 63, w = tid >> 6;
    const int wm = w & 1, wn = w >> 1;
    const int m0 = blockIdx.x * 128, n0 = blockIdx.y * 128;
    const int fr = lane & 15, fq = lane >> 4;

    const int str = lane >> 2;
    const int stk = ((lane & 3) ^ ((lane >> 3) & 3)) * 8;

    f32x4 acc[4][4] = {};

    for (int kt = 0; kt < K; kt += BK) {
#pragma unroll
        for (int c = 0; c < 2; ++c) {
            const int r  = w * 32 + c * 16 + str;
            const int lo = (w * 32 + c * 16) * BK;
            glds16(Ah + (size_t)(m0 + r) * K + kt + stk, sAh + lo);
            glds16(Al + (size_t)(m0 + r) * K + kt + stk, sAl + lo);
            glds16(Bh + (size_t)(n0 + r) * K + kt + stk, sBh + lo);
            glds16(Bl + (size_t)(n0 + r) * K + kt + stk, sBl + lo);
        }
        __syncthreads();

        short8 ah[4], al[4], bh[4], bl[4];
        const int kswz = (fq ^ ((fr >> 1) & 3)) * 8;
#pragma unroll
        for (int i = 0; i < 4; ++i) {
            const int ar = (wm * 64 + i * 16 + fr) * BK + kswz;
            const int br = (wn * 64 + i * 16 + fr) * BK + kswz;
            ah[i] = *(const short8*)(sAh + ar);
            al[i] = *(const short8*)(sAl + ar);
            bh[i] = *(const short8*)(sBh + br);
            bl[i] = *(const short8*)(sBl + br);
        }
#pragma unroll
        for (int i = 0; i < 4; ++i)
#pragma unroll
            for (int j = 0; j < 4; ++j) {
                asm("v_mfma_f32_16x16x32_bf16 %0, %1, %2, %0"
                    : "+v"(acc[i][j]) : "v"(ah[i]), "v"(bh[j]));
                asm("v_mfma_f32_16x16x32_bf16 %0, %1, %2, %0"
                    : "+v"(acc[i][j]) : "v"(ah[i]), "v"(bl[j]));
                asm("v_mfma_f32_16x16x32_bf16 %0, %1, %2, %0"
                    : "+v"(acc[i][j]) : "v"(al[i]), "v"(bh[j]));
            }
        __syncthreads();
    }
    asm volatile("s_nop 7\n\ts_nop 7");

    const bool isV = (MODE == 0) && (n0 >= 1280);
    const bool isK = (MODE == 0) && (n0 >= 1024) && (n0 < 1280);
#pragma unroll
    for (int i = 0; i < 4; ++i)
#pragma unroll
        for (int jj = 0; jj < 4; ++jj) {
            const int row = m0 + wm * 64 + i * 16 + fq * 4 + jj;
            float v0 = acc[i][0][jj], v1 = acc[i][1][jj];
            float v2 = acc[i][2][jj], v3 = acc[i][3][jj];
            if (MODE == 0 && !isV) {
                const int sb = (row & (S - 1)) * 64;
                // pairs (d, d+32): (v0@fr, v2@fr+32), (v1@16+fr, v3@48+fr)
                float r0 = v0 * Cos[sb + fr]      - v2 * Sin[sb + fr];
                float r2 = v2 * Cos[sb + fr + 32] + v0 * Sin[sb + fr + 32];
                float r1 = v1 * Cos[sb + fr + 16] - v3 * Sin[sb + fr + 16];
                float r3 = v3 * Cos[sb + fr + 48] + v1 * Sin[sb + fr + 48];
                r0 = phi(r0); r1 = phi(r1); r2 = phi(r2); r3 = phi(r3);
                if (isK) {
                    float mv = (float)Mask[row];
                    r0 *= mv; r1 *= mv; r2 *= mv; r3 *= mv;
                }
                v0 = r0; v1 = r1; v2 = r2; v3 = r3;
            }
            float* cr = &C[(size_t)row * ldc + n0 + wn * 64 + fr];
            cr[0]  = v0; cr[16] = v1; cr[32] = v2; cr[48] = v3;
        }
}

// ---------- split x (f32) -> hi bf16; LO FORCED TO ZERO (experiment) --------
__global__ __launch_bounds__(256) void split_x_k(
    const float* __restrict__ X, u16* __restrict__ H, u16* __restrict__ L)
{
    const int i = (blockIdx.x * 256 + threadIdx.x) * 4;
    float4 v = *reinterpret_cast<const float4*>(&X[i]);
    ushort4 h, l;
    h.x = f2bf(v.x); l.x = 0;
    h.y = f2bf(v.y); l.y = 0;
    h.z = f2bf(v.z); l.z = 0;
    h.w = f2bf(v.w); l.w = 0;
    *reinterpret_cast<ushort4*>(&H[i]) = h;
    *reinterpret_cast<ushort4*>(&L[i]) = l;
}

// ---------- transpose + split W; LO FORCED TO ZERO (experiment) -------------
__global__ __launch_bounds__(256) void wsplit_k(
    const float* __restrict__ W, int N,
    u16* __restrict__ Th, u16* __restrict__ Tl, int nbase)
{
    __shared__ float t[32][33];
    const int n0 = blockIdx.x * 32, k0 = blockIdx.y * 32;
    const int tx = threadIdx.x, ty = threadIdx.y;  // 32 x 8
#pragma unroll
    for (int i = 0; i < 4; ++i)
        t[ty + i * 8][tx] = W[(size_t)(k0 + ty + i * 8) * N + n0 + tx];
    __syncthreads();
#pragma unroll
    for (int i = 0; i < 4; ++i) {
        const int n = ty + i * 8;
        float v = t[tx][n];
        u16 h = f2bf(v);
        size_t o = (size_t)(nbase + n0 + n) * 1024 + k0 + tx;
        Th[o] = h;
        Tl[o] = 0;
    }
}

// ---------- stage1: per (group, 64-row chunk) partial KV + Ksum -------------
__global__ __launch_bounds__(256) void kv_stage1_k(
    const float* __restrict__ QKV, float* __restrict__ part)
{
    const int g  = blockIdx.x;             // b*4 + kvh
    const int ch = blockIdx.y;             // 32 chunks of 64 rows
    const int b  = g >> 2, kvh = g & 3;
    const int tid = threadIdx.x;

    __shared__ float ks[64][64];
    __shared__ float vs[64][64];
    const int m0 = b * S + ch * 64;
#pragma unroll
    for (int l = 0; l < 4; ++l) {
        int idx = tid + l * 256;           // 0..1023
        int r = idx >> 4, q4 = (idx & 15) * 4;
        const float* src = QKV + (size_t)(m0 + r) * QW + 1024 + kvh * 64;
        *reinterpret_cast<float4*>(&ks[r][q4]) = *reinterpret_cast<const float4*>(src + q4);
        *reinterpret_cast<float4*>(&vs[r][q4]) = *reinterpret_cast<const float4*>(src + 256 + q4);
    }
    __syncthreads();

    const int i = tid >> 2, j0 = (tid & 3) * 16;
    float4 a0 = {0,0,0,0}, a1 = {0,0,0,0}, a2 = {0,0,0,0}, a3 = {0,0,0,0};
#pragma unroll 8
    for (int r = 0; r < 64; ++r) {
        float kv = ks[r][i];
        float4 w0 = *reinterpret_cast<const float4*>(&vs[r][j0]);
        float4 w1 = *reinterpret_cast<const float4*>(&vs[r][j0 + 4]);
        float4 w2 = *reinterpret_cast<const float4*>(&vs[r][j0 + 8]);
        float4 w3 = *reinterpret_cast<const float4*>(&vs[r][j0 + 12]);
        a0.x = fmaf(kv, w0.x, a0.x); a0.y = fmaf(kv, w0.y, a0.y);
        a0.z = fmaf(kv, w0.z, a0.z); a0.w = fmaf(kv, w0.w, a0.w);
        a1.x = fmaf(kv, w1.x, a1.x); a1.y = fmaf(kv, w1.y, a1.y);
        a1.z = fmaf(kv, w1.z, a1.z); a1.w = fmaf(kv, w1.w, a1.w);
        a2.x = fmaf(kv, w2.x, a2.x); a2.y = fmaf(kv, w2.y, a2.y);
        a2.z = fmaf(kv, w2.z, a2.z); a2.w = fmaf(kv, w2.w, a2.w);
        a3.x = fmaf(kv, w3.x, a3.x); a3.y = fmaf(kv, w3.y, a3.y);
        a3.z = fmaf(kv, w3.z, a3.z); a3.w = fmaf(kv, w3.w, a3.w);
    }
    float* dst = part + ((size_t)g * 32 + ch) * 4160;
    float* d0 = dst + i * 64 + j0;
    *reinterpret_cast<float4*>(d0)      = a0;
    *reinterpret_cast<float4*>(d0 + 4)  = a1;
    *reinterpret_cast<float4*>(d0 + 8)  = a2;
    *reinterpret_cast<float4*>(d0 + 12) = a3;
    if (tid < 64) {
        float ksum = 0.f;
#pragma unroll 8
        for (int r = 0; r < 64; ++r) ksum += ks[r][tid];
        dst[4096 + tid] = ksum;
    }
}

// ---------- stage2: sum 32 partials; KV lo FORCED TO ZERO (experiment) ------
__global__ __launch_bounds__(256) void kv_reduce_k(
    const float* __restrict__ part, u16* __restrict__ KVh,
    u16* __restrict__ KVl, float* __restrict__ Ksumf)
{
    const int g = blockIdx.x;
    const int e = blockIdx.y * 256 + threadIdx.x;
    if (e >= 4160) return;
    const float* p = part + (size_t)g * 32 * 4160 + e;
    float s = 0.f;
#pragma unroll 8
    for (int c = 0; c < 32; ++c) s += p[(size_t)c * 4160];
    if (e < 4096) {
        u16 h = f2bf(s);
        KVh[g * 4096 + e] = h;
        KVl[g * 4096 + e] = 0;
    } else {
        Ksumf[g * 64 + (e - 4096)] = s;
    }
}

// ---------- KWT: byte-identical engine to round 3; KW lo FORCED TO ZERO -----
__global__ __launch_bounds__(256, 2) void kw_gemm_k(
    const u16* __restrict__ Woh, const u16* __restrict__ Wol,
    const u16* __restrict__ KVh, const u16* __restrict__ KVl,
    u16* __restrict__ KWh, u16* __restrict__ KWl)
{
    __shared__ __align__(16) u16 sAh[128 * 64], sAl[128 * 64];
    __shared__ __align__(16) u16 sBh[64 * 64],  sBl[64 * 64];

    const int tid = threadIdx.x, lane = tid & 63, w = tid >> 6;
    const int o0 = blockIdx.x * 128;
    const int gh = blockIdx.y, b = gh >> 4, h = gh & 15, g = b * 4 + (h >> 2);
    const int fr = lane & 15, fq = lane >> 4;
    const int srow = lane >> 3, sslot = lane & 7;
    const int sswz = (sslot ^ srow) * 8;

#pragma unroll
    for (int c = 0; c < 4; ++c) {                      // A: 128 rows
        const int rb = w * 32 + c * 8;
        const size_t go = (size_t)(o0 + rb + srow) * 1024 + h * 64 + sswz;
        glds16(Woh + go, sAh + rb * 64);
        glds16(Wol + go, sAl + rb * 64);
    }
#pragma unroll
    for (int c = 0; c < 2; ++c) {                      // B: 64 rows
        const int rb = w * 16 + c * 8;
        const size_t go = (size_t)g * 4096 + (rb + srow) * 64 + sswz;
        glds16(KVh + go, sBh + rb * 64);
        glds16(KVl + go, sBl + rb * 64);
    }
    __syncthreads();

    f32x4 acc[2][4] = {};
#pragma unroll
    for (int kk = 0; kk < 2; ++kk) {
        short8 a_h[2], a_l[2], b_h[4], b_l[4];
#pragma unroll
        for (int i = 0; i < 2; ++i) {
            const int row = w * 32 + i * 16 + fr;
            const int off = row * 64 + ((kk * 4 + fq) ^ (fr & 7)) * 8;
            a_h[i] = *(const short8*)(sAh + off);
            a_l[i] = *(const short8*)(sAl + off);
        }
#pragma unroll
        for (int j = 0; j < 4; ++j) {
            const int row = j * 16 + fr;
            const int off = row * 64 + ((kk * 4 + fq) ^ (fr & 7)) * 8;
            b_h[j] = *(const short8*)(sBh + off);
            b_l[j] = *(const short8*)(sBl + off);
        }
#pragma unroll
        for (int i = 0; i < 2; ++i)
#pragma unroll
            for (int j = 0; j < 4; ++j) {
                asm("v_mfma_f32_16x16x32_bf16 %0, %1, %2, %0"
                    : "+v"(acc[i][j]) : "v"(a_h[i]), "v"(b_h[j]));
                asm("v_mfma_f32_16x16x32_bf16 %0, %1, %2, %0"
                    : "+v"(acc[i][j]) : "v"(a_h[i]), "v"(b_l[j]));
                asm("v_mfma_f32_16x16x32_bf16 %0, %1, %2, %0"
                    : "+v"(acc[i][j]) : "v"(a_l[i]), "v"(b_h[j]));
            }
    }
    asm volatile("s_nop 7\n\ts_nop 7");
#pragma unroll
    for (int i = 0; i < 2; ++i)
#pragma unroll
        for (int j = 0; j < 4; ++j)
#pragma unroll
            for (int jj = 0; jj < 4; ++jj) {
                const int row = o0 + w * 32 + i * 16 + fq * 4 + jj;   // o
                const int col = j * 16 + fr;                          // i of KV
                float v = acc[i][j][jj];
                u16 hh = f2bf(v);
                size_t off = ((size_t)b * 1024 + row) * 1024 + h * 64 + col;
                KWh[off] = hh;
                KWl[off] = 0;
            }
}

// ---------- q_hat; LO FORCED TO ZERO (experiment) ----------
__global__ __launch_bounds__(256) void den_split_k(
    const float* __restrict__ QKV, const float* __restrict__ Ksumf,
    u16* __restrict__ Qh, u16* __restrict__ Ql)
{
    const int t = blockIdx.x * 256 + threadIdx.x;   // (m, h)
    const int m = t >> 4, h = t & 15;
    const int g = (m >> 11) * 4 + (h >> 2);
    const float* q  = QKV + (size_t)m * QW + h * 64;
    const float* Ks = Ksumf + g * 64;

    float4 qv[16];
    float den = 0.f;
#pragma unroll
    for (int c = 0; c < 16; ++c) {
        qv[c] = *reinterpret_cast<const float4*>(&q[c * 4]);
        den = fmaf(qv[c].x, Ks[c * 4 + 0], den);
        den = fmaf(qv[c].y, Ks[c * 4 + 1], den);
        den = fmaf(qv[c].z, Ks[c * 4 + 2], den);
        den = fmaf(qv[c].w, Ks[c * 4 + 3], den);
    }
    const float rd = 1.f / fmaxf(den, 1e-6f);
    const size_t o = (size_t)m * 1024 + h * 64;
#pragma unroll
    for (int c = 0; c < 16; ++c) {
        float x0 = qv[c].x * rd, x1 = qv[c].y * rd;
        float x2 = qv[c].z * rd, x3 = qv[c].w * rd;
        ushort4 hh, ll;
        hh.x = f2bf(x0); ll.x = 0;
        hh.y = f2bf(x1); ll.y = 0;
        hh.z = f2bf(x2); ll.z = 0;
        hh.w = f2bf(x3); ll.w = 0;
        *reinterpret_cast<ushort4*>(&Qh[o + c * 4]) = hh;
        *reinterpret_cast<ushort4*>(&Ql[o + c * 4]) = ll;
    }
}

extern "C" void kernel_launch(void* const* d_in, const int* in_sizes, int n_in,
                              void* d_out, int out_size, void* d_ws, size_t ws_size,
                              hipStream_t stream)
{
    const float* x    = (const float*)d_in[0];
    const float* cosp = (const float*)d_in[1];
    const float* sinp = (const float*)d_in[2];
    const int*   msk  = (const int*)d_in[3];
    const float* Wq   = (const float*)d_in[4];
    const float* Wk   = (const float*)d_in[5];
    const float* Wv   = (const float*)d_in[6];
    const float* Wo   = (const float*)d_in[7];
    float* out = (float*)d_out;

    // ---- workspace layout (identical to round 3) ----
    float* qkv   = (float*)d_ws;                      // [4096][1536]
    float* part  = qkv + (size_t)M * QW;              // [8][32][4160]
    float* ksumf = part + (size_t)8 * 32 * 4160;      // [8][64]
    u16* xh  = (u16*)(ksumf + 512);                   // [4096][1024]
    u16* xl  = xh  + (size_t)M * K;
    u16* bth = xl  + (size_t)M * K;                   // [1536][1024]
    u16* btl = bth + (size_t)1536 * K;
    u16* woh = btl + (size_t)1536 * K;                // [1024][1024] Wo^T
    u16* wol = woh + (size_t)K * K;
    u16* kvh = wol + (size_t)K * K;                   // [8][4096]
    u16* kvl = kvh + 8 * 4096;
    u16* kwh = kvl + 8 * 4096;                        // [2][1024][1024]
    u16* kwl = kwh + (size_t)2 * K * K;
    u16* qh  = xh;                                    // alias (x consumed)
    u16* ql  = xl;

    // 1) precision splits (lo = 0 everywhere: values == single-bf16 pipeline)
    split_x_k<<<(M * K) / 1024, 256, 0, stream>>>(x, xh, xl);
    dim3 wb(32, 8);
    wsplit_k<<<dim3(32, 32), wb, 0, stream>>>(Wq, 1024, bth, btl, 0);
    wsplit_k<<<dim3(8, 32),  wb, 0, stream>>>(Wk, 256,  bth, btl, 1024);
    wsplit_k<<<dim3(8, 32),  wb, 0, stream>>>(Wv, 256,  bth, btl, 1280);
    wsplit_k<<<dim3(32, 32), wb, 0, stream>>>(Wo, 1024, woh, wol, 0);

    // 2) QKV = x @ [Wq|Wk|Wv] with fused RoPE + phi (+mask on k)
    gemm3_k<0><<<dim3(M / 128, QW / 128, 1), 256, 0, stream>>>(
        xh, xl, bth, btl, qkv, QW, 0, 0, 0, cosp, sinp, msk);

    // 3) KV & Ksum (atomic-free two-stage)
    kv_stage1_k<<<dim3(8, 32), 256, 0, stream>>>(qkv, part);
    kv_reduce_k<<<dim3(8, 17), 256, 0, stream>>>(part, kvh, kvl, ksumf);

    // 4) KWT[b] = per-head KV @ Wo slices
    kw_gemm_k<<<dim3(8, 32), 256, 0, stream>>>(woh, wol, kvh, kvl, kwh, kwl);

    // 5) q_hat = q~ / den -> bf16 (lo = 0)
    den_split_k<<<(M * 16) / 256, 256, 0, stream>>>(qkv, ksumf, qh, ql);

    // 6) out_b = q_hat_b @ KWT_b^T
    gemm3_k<1><<<dim3(2048 / 128, HID / 128, 2), 256, 0, stream>>>(
        qh, ql, kwh, kwl, out, HID, 2048, 1024, 2048,
        nullptr, nullptr, nullptr);
}

// Round 7
// 99.481 us; speedup vs baseline: 4.0963x; 1.3735x over previous
//
#include <hip/hip_runtime.h>
#include <hip/hip_bf16.h>

using u16 = unsigned short;
using u32 = unsigned int;

namespace {
constexpr int S   = 2048;
constexpr int HID = 1024;
constexpr int M   = 4096;                  // B*S
constexpr int QW  = 1536;                  // q(1024) | k(256) | v(256)
constexpr int K   = 1024;                  // inner dim of both big GEMMs
}

typedef __attribute__((ext_vector_type(8))) short short8;   // 8 bf16 = 4 VGPR
typedef __attribute__((ext_vector_type(4))) float f32x4;

__device__ __forceinline__ u16 f2bf(float f) {
    u32 u = __builtin_bit_cast(u32, f);
    u += 0x7fffu + ((u >> 16) & 1u);       // RNE
    return (u16)(u >> 16);
}
__device__ __forceinline__ float bf2f(u16 h) {
    return __builtin_bit_cast(float, (u32)h << 16);
}
__device__ __forceinline__ float phi(float x) {   // elu(x)+1
    return x > 0.f ? x + 1.f : __expf(x);
}
__device__ __forceinline__ void glds16(const u16* g, u16* l) {
    __builtin_amdgcn_global_load_lds(
        (const __attribute__((address_space(1))) u32*)g,
        (__attribute__((address_space(3))) u32*)l, 16, 0, 0);
}

// ---------- single-bf16 MFMA GEMM (builtin MFMA, explicit vmcnt drain) -----
// MODE 0: fused RoPE+phi epilogue (QKV projection; k-cols masked, v pass).
// MODE 1: plain C write. z-grid offsets rows by zAr/zBr/zCr per blockIdx.z.
template <int MODE>
__global__ __launch_bounds__(256, 2) void gemm3_k(
    const u16* __restrict__ Ah, const u16* __restrict__ Bh,
    float* __restrict__ C, int ldc, int zAr, int zBr, int zCr,
    const float* __restrict__ Cos, const float* __restrict__ Sin,
    const int* __restrict__ Mask)
{
    constexpr int BK = 32;
    __shared__ __align__(16) u16 sAh[128 * BK];
    __shared__ __align__(16) u16 sBh[128 * BK];

    Ah += (size_t)blockIdx.z * zAr * K;
    Bh += (size_t)blockIdx.z * zBr * K;
    C  += (size_t)blockIdx.z * zCr * ldc;

    const int tid  = threadIdx.x;
    const int lane = tid & 63, w = tid >> 6;
    const int wm = w & 1, wn = w >> 1;
    const int m0 = blockIdx.x * 128, n0 = blockIdx.y * 128;
    const int fr = lane & 15, fq = lane >> 4;

    const int str = lane >> 2;
    const int stk = ((lane & 3) ^ ((lane >> 3) & 3)) * 8;

    f32x4 acc[4][4] = {};

    for (int kt = 0; kt < K; kt += BK) {
#pragma unroll
        for (int c = 0; c < 2; ++c) {
            const int r  = w * 32 + c * 16 + str;
            const int lo = (w * 32 + c * 16) * BK;
            glds16(Ah + (size_t)(m0 + r) * K + kt + stk, sAh + lo);
            glds16(Bh + (size_t)(n0 + r) * K + kt + stk, sBh + lo);
        }
        asm volatile("s_waitcnt vmcnt(0)" ::: "memory");   // drain DMA->LDS
        __syncthreads();

        short8 ah[4], bh[4];
        const int kswz = (fq ^ ((fr >> 1) & 3)) * 8;
#pragma unroll
        for (int i = 0; i < 4; ++i) {
            const int ar = (wm * 64 + i * 16 + fr) * BK + kswz;
            const int br = (wn * 64 + i * 16 + fr) * BK + kswz;
            ah[i] = *(const short8*)(sAh + ar);
            bh[i] = *(const short8*)(sBh + br);
        }
#pragma unroll
        for (int i = 0; i < 4; ++i)
#pragma unroll
            for (int j = 0; j < 4; ++j)
                acc[i][j] = __builtin_amdgcn_mfma_f32_16x16x32_bf16(
                    ah[i], bh[j], acc[i][j], 0, 0, 0);
        __syncthreads();
    }

    const bool isV = (MODE == 0) && (n0 >= 1280);
    const bool isK = (MODE == 0) && (n0 >= 1024) && (n0 < 1280);
#pragma unroll
    for (int i = 0; i < 4; ++i)
#pragma unroll
        for (int jj = 0; jj < 4; ++jj) {
            const int row = m0 + wm * 64 + i * 16 + fq * 4 + jj;
            float v0 = acc[i][0][jj], v1 = acc[i][1][jj];
            float v2 = acc[i][2][jj], v3 = acc[i][3][jj];
            if (MODE == 0 && !isV) {
                const int sb = (row & (S - 1)) * 64;
                // pairs (d, d+32): (v0@fr, v2@fr+32), (v1@16+fr, v3@48+fr)
                float r0 = v0 * Cos[sb + fr]      - v2 * Sin[sb + fr];
                float r2 = v2 * Cos[sb + fr + 32] + v0 * Sin[sb + fr + 32];
                float r1 = v1 * Cos[sb + fr + 16] - v3 * Sin[sb + fr + 16];
                float r3 = v3 * Cos[sb + fr + 48] + v1 * Sin[sb + fr + 48];
                r0 = phi(r0); r1 = phi(r1); r2 = phi(r2); r3 = phi(r3);
                if (isK) {
                    float mv = (float)Mask[row];
                    r0 *= mv; r1 *= mv; r2 *= mv; r3 *= mv;
                }
                v0 = r0; v1 = r1; v2 = r2; v3 = r3;
            }
            float* cr = &C[(size_t)row * ldc + n0 + wn * 64 + fr];
            cr[0]  = v0; cr[16] = v1; cr[32] = v2; cr[48] = v3;
        }
}

// ---------- split x (f32) -> hi bf16; lo kept zero (kw path reads lo=0) -----
__global__ __launch_bounds__(256) void split_x_k(
    const float* __restrict__ X, u16* __restrict__ H, u16* __restrict__ L)
{
    const int i = (blockIdx.x * 256 + threadIdx.x) * 4;
    float4 v = *reinterpret_cast<const float4*>(&X[i]);
    ushort4 h, l;
    h.x = f2bf(v.x); l.x = 0;
    h.y = f2bf(v.y); l.y = 0;
    h.z = f2bf(v.z); l.z = 0;
    h.w = f2bf(v.w); l.w = 0;
    *reinterpret_cast<ushort4*>(&H[i]) = h;
    *reinterpret_cast<ushort4*>(&L[i]) = l;
}

// ---------- transpose + split W; lo = 0 -------------------------------------
__global__ __launch_bounds__(256) void wsplit_k(
    const float* __restrict__ W, int N,
    u16* __restrict__ Th, u16* __restrict__ Tl, int nbase)
{
    __shared__ float t[32][33];
    const int n0 = blockIdx.x * 32, k0 = blockIdx.y * 32;
    const int tx = threadIdx.x, ty = threadIdx.y;  // 32 x 8
#pragma unroll
    for (int i = 0; i < 4; ++i)
        t[ty + i * 8][tx] = W[(size_t)(k0 + ty + i * 8) * N + n0 + tx];
    __syncthreads();
#pragma unroll
    for (int i = 0; i < 4; ++i) {
        const int n = ty + i * 8;
        float v = t[tx][n];
        u16 h = f2bf(v);
        size_t o = (size_t)(nbase + n0 + n) * 1024 + k0 + tx;
        Th[o] = h;
        Tl[o] = 0;
    }
}

// ---------- stage1: per (group, 64-row chunk) partial KV + Ksum -------------
__global__ __launch_bounds__(256) void kv_stage1_k(
    const float* __restrict__ QKV, float* __restrict__ part)
{
    const int g  = blockIdx.x;             // b*4 + kvh
    const int ch = blockIdx.y;             // 32 chunks of 64 rows
    const int b  = g >> 2, kvh = g & 3;
    const int tid = threadIdx.x;

    __shared__ float ks[64][64];
    __shared__ float vs[64][64];
    const int m0 = b * S + ch * 64;
#pragma unroll
    for (int l = 0; l < 4; ++l) {
        int idx = tid + l * 256;           // 0..1023
        int r = idx >> 4, q4 = (idx & 15) * 4;
        const float* src = QKV + (size_t)(m0 + r) * QW + 1024 + kvh * 64;
        *reinterpret_cast<float4*>(&ks[r][q4]) = *reinterpret_cast<const float4*>(src + q4);
        *reinterpret_cast<float4*>(&vs[r][q4]) = *reinterpret_cast<const float4*>(src + 256 + q4);
    }
    __syncthreads();

    const int i = tid >> 2, j0 = (tid & 3) * 16;
    float4 a0 = {0,0,0,0}, a1 = {0,0,0,0}, a2 = {0,0,0,0}, a3 = {0,0,0,0};
#pragma unroll 8
    for (int r = 0; r < 64; ++r) {
        float kv = ks[r][i];
        float4 w0 = *reinterpret_cast<const float4*>(&vs[r][j0]);
        float4 w1 = *reinterpret_cast<const float4*>(&vs[r][j0 + 4]);
        float4 w2 = *reinterpret_cast<const float4*>(&vs[r][j0 + 8]);
        float4 w3 = *reinterpret_cast<const float4*>(&vs[r][j0 + 12]);
        a0.x = fmaf(kv, w0.x, a0.x); a0.y = fmaf(kv, w0.y, a0.y);
        a0.z = fmaf(kv, w0.z, a0.z); a0.w = fmaf(kv, w0.w, a0.w);
        a1.x = fmaf(kv, w1.x, a1.x); a1.y = fmaf(kv, w1.y, a1.y);
        a1.z = fmaf(kv, w1.z, a1.z); a1.w = fmaf(kv, w1.w, a1.w);
        a2.x = fmaf(kv, w2.x, a2.x); a2.y = fmaf(kv, w2.y, a2.y);
        a2.z = fmaf(kv, w2.z, a2.z); a2.w = fmaf(kv, w2.w, a2.w);
        a3.x = fmaf(kv, w3.x, a3.x); a3.y = fmaf(kv, w3.y, a3.y);
        a3.z = fmaf(kv, w3.z, a3.z); a3.w = fmaf(kv, w3.w, a3.w);
    }
    float* dst = part + ((size_t)g * 32 + ch) * 4160;
    float* d0 = dst + i * 64 + j0;
    *reinterpret_cast<float4*>(d0)      = a0;
    *reinterpret_cast<float4*>(d0 + 4)  = a1;
    *reinterpret_cast<float4*>(d0 + 8)  = a2;
    *reinterpret_cast<float4*>(d0 + 12) = a3;
    if (tid < 64) {
        float ksum = 0.f;
#pragma unroll 8
        for (int r = 0; r < 64; ++r) ksum += ks[r][tid];
        dst[4096 + tid] = ksum;
    }
}

// ---------- stage2: sum 32 partials; KV -> bf16 (lo=0), Ksum -> f32 ---------
__global__ __launch_bounds__(256) void kv_reduce_k(
    const float* __restrict__ part, u16* __restrict__ KVh,
    u16* __restrict__ KVl, float* __restrict__ Ksumf)
{
    const int g = blockIdx.x;
    const int e = blockIdx.y * 256 + threadIdx.x;
    if (e >= 4160) return;
    const float* p = part + (size_t)g * 32 * 4160 + e;
    float s = 0.f;
#pragma unroll 8
    for (int c = 0; c < 32; ++c) s += p[(size_t)c * 4160];
    if (e < 4096) {
        u16 h = f2bf(s);
        KVh[g * 4096 + e] = h;
        KVl[g * 4096 + e] = 0;
    } else {
        Ksumf[g * 64 + (e - 4096)] = s;
    }
}

// ---------- KWT: byte-identical engine to round 6 (3-MFMA, lo=0 data) -------
__global__ __launch_bounds__(256, 2) void kw_gemm_k(
    const u16* __restrict__ Woh, const u16* __restrict__ Wol,
    const u16* __restrict__ KVh, const u16* __restrict__ KVl,
    u16* __restrict__ KWh, u16* __restrict__ KWl)
{
    __shared__ __align__(16) u16 sAh[128 * 64], sAl[128 * 64];
    __shared__ __align__(16) u16 sBh[64 * 64],  sBl[64 * 64];

    const int tid = threadIdx.x, lane = tid & 63, w = tid >> 6;
    const int o0 = blockIdx.x * 128;
    const int gh = blockIdx.y, b = gh >> 4, h = gh & 15, g = b * 4 + (h >> 2);
    const int fr = lane & 15, fq = lane >> 4;
    const int srow = lane >> 3, sslot = lane & 7;
    const int sswz = (sslot ^ srow) * 8;

#pragma unroll
    for (int c = 0; c < 4; ++c) {                      // A: 128 rows
        const int rb = w * 32 + c * 8;
        const size_t go = (size_t)(o0 + rb + srow) * 1024 + h * 64 + sswz;
        glds16(Woh + go, sAh + rb * 64);
        glds16(Wol + go, sAl + rb * 64);
    }
#pragma unroll
    for (int c = 0; c < 2; ++c) {                      // B: 64 rows
        const int rb = w * 16 + c * 8;
        const size_t go = (size_t)g * 4096 + (rb + srow) * 64 + sswz;
        glds16(KVh + go, sBh + rb * 64);
        glds16(KVl + go, sBl + rb * 64);
    }
    __syncthreads();

    f32x4 acc[2][4] = {};
#pragma unroll
    for (int kk = 0; kk < 2; ++kk) {
        short8 a_h[2], a_l[2], b_h[4], b_l[4];
#pragma unroll
        for (int i = 0; i < 2; ++i) {
            const int row = w * 32 + i * 16 + fr;
            const int off = row * 64 + ((kk * 4 + fq) ^ (fr & 7)) * 8;
            a_h[i] = *(const short8*)(sAh + off);
            a_l[i] = *(const short8*)(sAl + off);
        }
#pragma unroll
        for (int j = 0; j < 4; ++j) {
            const int row = j * 16 + fr;
            const int off = row * 64 + ((kk * 4 + fq) ^ (fr & 7)) * 8;
            b_h[j] = *(const short8*)(sBh + off);
            b_l[j] = *(const short8*)(sBl + off);
        }
#pragma unroll
        for (int i = 0; i < 2; ++i)
#pragma unroll
            for (int j = 0; j < 4; ++j) {
                asm("v_mfma_f32_16x16x32_bf16 %0, %1, %2, %0"
                    : "+v"(acc[i][j]) : "v"(a_h[i]), "v"(b_h[j]));
                asm("v_mfma_f32_16x16x32_bf16 %0, %1, %2, %0"
                    : "+v"(acc[i][j]) : "v"(a_h[i]), "v"(b_l[j]));
                asm("v_mfma_f32_16x16x32_bf16 %0, %1, %2, %0"
                    : "+v"(acc[i][j]) : "v"(a_l[i]), "v"(b_h[j]));
            }
    }
    asm volatile("s_nop 7\n\ts_nop 7");
#pragma unroll
    for (int i = 0; i < 2; ++i)
#pragma unroll
        for (int j = 0; j < 4; ++j)
#pragma unroll
            for (int jj = 0; jj < 4; ++jj) {
                const int row = o0 + w * 32 + i * 16 + fq * 4 + jj;   // o
                const int col = j * 16 + fr;                          // i of KV
                float v = acc[i][j][jj];
                u16 hh = f2bf(v);
                size_t off = ((size_t)b * 1024 + row) * 1024 + h * 64 + col;
                KWh[off] = hh;
                KWl[off] = 0;
            }
}

// ---------- q_hat = q~ / max(q~.Ksum, 1e-6) -> bf16 (lo = 0) ----------
__global__ __launch_bounds__(256) void den_split_k(
    const float* __restrict__ QKV, const float* __restrict__ Ksumf,
    u16* __restrict__ Qh, u16* __restrict__ Ql)
{
    const int t = blockIdx.x * 256 + threadIdx.x;   // (m, h)
    const int m = t >> 4, h = t & 15;
    const int g = (m >> 11) * 4 + (h >> 2);
    const float* q  = QKV + (size_t)m * QW + h * 64;
    const float* Ks = Ksumf + g * 64;

    float4 qv[16];
    float den = 0.f;
#pragma unroll
    for (int c = 0; c < 16; ++c) {
        qv[c] = *reinterpret_cast<const float4*>(&q[c * 4]);
        den = fmaf(qv[c].x, Ks[c * 4 + 0], den);
        den = fmaf(qv[c].y, Ks[c * 4 + 1], den);
        den = fmaf(qv[c].z, Ks[c * 4 + 2], den);
        den = fmaf(qv[c].w, Ks[c * 4 + 3], den);
    }
    const float rd = 1.f / fmaxf(den, 1e-6f);
    const size_t o = (size_t)m * 1024 + h * 64;
#pragma unroll
    for (int c = 0; c < 16; ++c) {
        float x0 = qv[c].x * rd, x1 = qv[c].y * rd;
        float x2 = qv[c].z * rd, x3 = qv[c].w * rd;
        ushort4 hh, ll;
        hh.x = f2bf(x0); ll.x = 0;
        hh.y = f2bf(x1); ll.y = 0;
        hh.z = f2bf(x2); ll.z = 0;
        hh.w = f2bf(x3); ll.w = 0;
        *reinterpret_cast<ushort4*>(&Qh[o + c * 4]) = hh;
        *reinterpret_cast<ushort4*>(&Ql[o + c * 4]) = ll;
    }
}

extern "C" void kernel_launch(void* const* d_in, const int* in_sizes, int n_in,
                              void* d_out, int out_size, void* d_ws, size_t ws_size,
                              hipStream_t stream)
{
    const float* x    = (const float*)d_in[0];
    const float* cosp = (const float*)d_in[1];
    const float* sinp = (const float*)d_in[2];
    const int*   msk  = (const int*)d_in[3];
    const float* Wq   = (const float*)d_in[4];
    const float* Wk   = (const float*)d_in[5];
    const float* Wv   = (const float*)d_in[6];
    const float* Wo   = (const float*)d_in[7];
    float* out = (float*)d_out;

    // ---- workspace layout (identical to round 6) ----
    float* qkv   = (float*)d_ws;                      // [4096][1536]
    float* part  = qkv + (size_t)M * QW;              // [8][32][4160]
    float* ksumf = part + (size_t)8 * 32 * 4160;      // [8][64]
    u16* xh  = (u16*)(ksumf + 512);                   // [4096][1024]
    u16* xl  = xh  + (size_t)M * K;
    u16* bth = xl  + (size_t)M * K;                   // [1536][1024]
    u16* btl = bth + (size_t)1536 * K;
    u16* woh = btl + (size_t)1536 * K;                // [1024][1024] Wo^T
    u16* wol = woh + (size_t)K * K;
    u16* kvh = wol + (size_t)K * K;                   // [8][4096]
    u16* kvl = kvh + 8 * 4096;
    u16* kwh = kvl + 8 * 4096;                        // [2][1024][1024]
    u16* kwl = kwh + (size_t)2 * K * K;
    u16* qh  = xh;                                    // alias (x consumed)
    u16* ql  = xl;

    // 1) precision splits (lo = 0; only kw path consumes lo)
    split_x_k<<<(M * K) / 1024, 256, 0, stream>>>(x, xh, xl);
    dim3 wb(32, 8);
    wsplit_k<<<dim3(32, 32), wb, 0, stream>>>(Wq, 1024, bth, btl, 0);
    wsplit_k<<<dim3(8, 32),  wb, 0, stream>>>(Wk, 256,  bth, btl, 1024);
    wsplit_k<<<dim3(8, 32),  wb, 0, stream>>>(Wv, 256,  bth, btl, 1280);
    wsplit_k<<<dim3(32, 32), wb, 0, stream>>>(Wo, 1024, woh, wol, 0);

    // 2) QKV = x @ [Wq|Wk|Wv] with fused RoPE + phi (+mask on k)
    gemm3_k<0><<<dim3(M / 128, QW / 128, 1), 256, 0, stream>>>(
        xh, bth, qkv, QW, 0, 0, 0, cosp, sinp, msk);

    // 3) KV & Ksum (atomic-free two-stage)
    kv_stage1_k<<<dim3(8, 32), 256, 0, stream>>>(qkv, part);
    kv_reduce_k<<<dim3(8, 17), 256, 0, stream>>>(part, kvh, kvl, ksumf);

    // 4) KWT[b] = per-head KV @ Wo slices
    kw_gemm_k<<<dim3(8, 32), 256, 0, stream>>>(woh, wol, kvh, kvl, kwh, kwl);

    // 5) q_hat = q~ / den -> bf16
    den_split_k<<<(M * 16) / 256, 256, 0, stream>>>(qkv, ksumf, qh, ql);

    // 6) out_b = q_hat_b @ KWT_b^T
    gemm3_k<1><<<dim3(2048 / 128, HID / 128, 2), 256, 0, stream>>>(
        qh, kwh, out, HID, 2048, 1024, 2048,
        nullptr, nullptr, nullptr);
}

// Round 8
// 85.075 us; speedup vs baseline: 4.7899x; 1.1693x over previous
//
#include <hip/hip_runtime.h>
#include <hip/hip_bf16.h>

using u16 = unsigned short;
using u32 = unsigned int;

namespace {
constexpr int S   = 2048;
constexpr int HID = 1024;
constexpr int M   = 4096;                  // B*S
constexpr int K   = 1024;                  // inner dim of both big GEMMs
}

typedef __attribute__((ext_vector_type(8))) short short8;   // 8 bf16 = 4 VGPR
typedef __attribute__((ext_vector_type(4))) float f32x4;

__device__ __forceinline__ u16 f2bf(float f) {
    u32 u = __builtin_bit_cast(u32, f);
    u += 0x7fffu + ((u >> 16) & 1u);       // RNE
    return (u16)(u >> 16);
}
__device__ __forceinline__ float bf2f(u16 h) {
    return __builtin_bit_cast(float, (u32)h << 16);
}
__device__ __forceinline__ float phi(float x) {   // elu(x)+1
    return x > 0.f ? x + 1.f : __expf(x);
}
__device__ __forceinline__ void glds16(const u16* g, u16* l) {
    __builtin_amdgcn_global_load_lds(
        (const __attribute__((address_space(1))) u32*)g,
        (__attribute__((address_space(3))) u32*)l, 16, 0, 0);
}

// ---------- single-bf16 MFMA GEMM, 128x128, BK=32, double-buffered LDS -----
// MODE 0: QKV projection. Epilogue: q tiles (n0<1024) -> rope+phi -> bf16 Cq;
//         k tiles -> rope+phi*mask -> f32 Ckv[.][0..255]; v -> Ckv[.][256..511].
// MODE 1: plain f32 C write, z-batched via zAr/zBr/zCr row offsets.
template <int MODE>
__global__ __launch_bounds__(256, 2) void gemm_k(
    const u16* __restrict__ A, const u16* __restrict__ B,
    u16* __restrict__ Cq, float* __restrict__ Ckv,
    float* __restrict__ Cf, int ldc, int zAr, int zBr, int zCr,
    const float* __restrict__ Cos, const float* __restrict__ Sin,
    const int* __restrict__ Mask)
{
    constexpr int BK = 32;
    constexpr int NT = K / BK;                     // 32 K-tiles
    __shared__ __align__(16) u16 sA0[128 * BK], sA1[128 * BK];
    __shared__ __align__(16) u16 sB0[128 * BK], sB1[128 * BK];

    A += (size_t)blockIdx.z * zAr * K;
    B += (size_t)blockIdx.z * zBr * K;
    if (MODE == 1) Cf += (size_t)blockIdx.z * zCr * ldc;

    const int tid  = threadIdx.x;
    const int lane = tid & 63, w = tid >> 6;
    const int wm = w & 1, wn = w >> 1;
    const int m0 = blockIdx.x * 128, n0 = blockIdx.y * 128;
    const int fr = lane & 15, fq = lane >> 4;

    const int str = lane >> 2;                     // staging row 0..15
    const int stk = ((lane & 3) ^ ((lane >> 3) & 3)) * 8;  // swizzled k-slot

    const u16* Ab = A + (size_t)(m0 + w * 32 + str) * K + stk;
    const u16* Bb = B + (size_t)(n0 + w * 32 + str) * K + stk;
    const int lo0 = (w * 32) * BK, lo1 = (w * 32 + 16) * BK;

    f32x4 acc[4][4] = {};
    const int kswz = (fq ^ ((fr >> 1) & 3)) * 8;

#define STAGE(dA, dB, kt)                                   \
    do {                                                    \
        glds16(Ab + (kt),              dA + lo0);           \
        glds16(Ab + (size_t)16 * K + (kt), dA + lo1);       \
        glds16(Bb + (kt),              dB + lo0);           \
        glds16(Bb + (size_t)16 * K + (kt), dB + lo1);       \
    } while (0)

#define COMPUTE(sAc, sBc)                                                   \
    do {                                                                    \
        short8 ah[4], bh[4];                                                \
        _Pragma("unroll")                                                   \
        for (int i = 0; i < 4; ++i) {                                       \
            ah[i] = *(const short8*)(sAc + (wm * 64 + i * 16 + fr) * BK + kswz); \
            bh[i] = *(const short8*)(sBc + (wn * 64 + i * 16 + fr) * BK + kswz); \
        }                                                                   \
        _Pragma("unroll")                                                   \
        for (int i = 0; i < 4; ++i)                                         \
            _Pragma("unroll")                                               \
            for (int j = 0; j < 4; ++j)                                     \
                acc[i][j] = __builtin_amdgcn_mfma_f32_16x16x32_bf16(        \
                    ah[i], bh[j], acc[i][j], 0, 0, 0);                      \
    } while (0)

#define SYNC()                                              \
    do {                                                    \
        asm volatile("s_waitcnt vmcnt(0)" ::: "memory");    \
        __syncthreads();                                    \
    } while (0)

    STAGE(sA0, sB0, 0);
    SYNC();
    for (int t = 0; t < NT; t += 2) {
        if (t + 1 < NT) STAGE(sA1, sB1, (t + 1) * BK);     // prefetch t+1
        COMPUTE(sA0, sB0);                                  // compute t
        SYNC();
        if (t + 2 < NT) STAGE(sA0, sB0, (t + 2) * BK);     // prefetch t+2
        COMPUTE(sA1, sB1);                                  // compute t+1
        SYNC();
    }
#undef STAGE
#undef COMPUTE
#undef SYNC

    const bool isQ = (MODE == 0) && (n0 < 1024);
    const bool isK = (MODE == 0) && (n0 >= 1024) && (n0 < 1280);
#pragma unroll
    for (int i = 0; i < 4; ++i)
#pragma unroll
        for (int jj = 0; jj < 4; ++jj) {
            const int row = m0 + wm * 64 + i * 16 + fq * 4 + jj;
            float v0 = acc[i][0][jj], v1 = acc[i][1][jj];
            float v2 = acc[i][2][jj], v3 = acc[i][3][jj];
            if (MODE == 1) {
                float* cr = &Cf[(size_t)row * ldc + n0 + wn * 64 + fr];
                cr[0] = v0; cr[16] = v1; cr[32] = v2; cr[48] = v3;
                continue;
            }
            if (isQ || isK) {                      // rope + phi (head-aligned)
                const int sb = (row & (S - 1)) * 64;
                // pairs (d, d+32): (v0@fr, v2@fr+32), (v1@16+fr, v3@48+fr)
                float r0 = v0 * Cos[sb + fr]      - v2 * Sin[sb + fr];
                float r2 = v2 * Cos[sb + fr + 32] + v0 * Sin[sb + fr + 32];
                float r1 = v1 * Cos[sb + fr + 16] - v3 * Sin[sb + fr + 16];
                float r3 = v3 * Cos[sb + fr + 48] + v1 * Sin[sb + fr + 48];
                v0 = phi(r0); v1 = phi(r1); v2 = phi(r2); v3 = phi(r3);
            }
            if (isQ) {
                u16* cr = &Cq[(size_t)row * 1024 + n0 + wn * 64 + fr];
                cr[0]  = f2bf(v0); cr[16] = f2bf(v1);
                cr[32] = f2bf(v2); cr[48] = f2bf(v3);
            } else if (isK) {
                const float mv = (float)Mask[row];
                float* cr = &Ckv[(size_t)row * 512 + (n0 - 1024) + wn * 64 + fr];
                cr[0] = v0 * mv; cr[16] = v1 * mv;
                cr[32] = v2 * mv; cr[48] = v3 * mv;
            } else {                               // v passthrough
                float* cr = &Ckv[(size_t)row * 512 + 256 + (n0 - 1280) + wn * 64 + fr];
                cr[0] = v0; cr[16] = v1; cr[32] = v2; cr[48] = v3;
            }
        }
}

// ---------- x (f32) -> bf16 ----------
__global__ __launch_bounds__(256) void split_x_k(
    const float* __restrict__ X, u16* __restrict__ H)
{
    const int i = (blockIdx.x * 256 + threadIdx.x) * 4;
    float4 v = *reinterpret_cast<const float4*>(&X[i]);
    ushort4 h;
    h.x = f2bf(v.x);
    h.y = f2bf(v.y);
    h.z = f2bf(v.z);
    h.w = f2bf(v.w);
    *reinterpret_cast<ushort4*>(&H[i]) = h;
}

// ---------- transpose W [K][N] f32 -> T rows [nbase+n][1024] bf16 -----------
__global__ __launch_bounds__(256) void wsplit_k(
    const float* __restrict__ W, int N,
    u16* __restrict__ Th, int nbase)
{
    __shared__ float t[32][33];
    const int n0 = blockIdx.x * 32, k0 = blockIdx.y * 32;
    const int tx = threadIdx.x, ty = threadIdx.y;  // 32 x 8
#pragma unroll
    for (int i = 0; i < 4; ++i)
        t[ty + i * 8][tx] = W[(size_t)(k0 + ty + i * 8) * N + n0 + tx];
    __syncthreads();
#pragma unroll
    for (int i = 0; i < 4; ++i) {
        const int n = ty + i * 8;
        Th[(size_t)(nbase + n0 + n) * 1024 + k0 + tx] = f2bf(t[tx][n]);
    }
}

// ---------- stage1: per (group, 64-row chunk) partial KV + Ksum -------------
__global__ __launch_bounds__(256) void kv_stage1_k(
    const float* __restrict__ KVf, float* __restrict__ part)
{
    const int g  = blockIdx.x;             // b*4 + kvh
    const int ch = blockIdx.y;             // 32 chunks of 64 rows
    const int b  = g >> 2, kvh = g & 3;
    const int tid = threadIdx.x;

    __shared__ float ks[64][64];
    __shared__ float vs[64][64];
    const int m0 = b * S + ch * 64;
#pragma unroll
    for (int l = 0; l < 4; ++l) {
        int idx = tid + l * 256;           // 0..1023
        int r = idx >> 4, q4 = (idx & 15) * 4;
        const float* src = KVf + (size_t)(m0 + r) * 512 + kvh * 64;
        *reinterpret_cast<float4*>(&ks[r][q4]) = *reinterpret_cast<const float4*>(src + q4);
        *reinterpret_cast<float4*>(&vs[r][q4]) = *reinterpret_cast<const float4*>(src + 256 + q4);
    }
    __syncthreads();

    const int i = tid >> 2, j0 = (tid & 3) * 16;
    float4 a0 = {0,0,0,0}, a1 = {0,0,0,0}, a2 = {0,0,0,0}, a3 = {0,0,0,0};
#pragma unroll 8
    for (int r = 0; r < 64; ++r) {
        float kv = ks[r][i];
        float4 w0 = *reinterpret_cast<const float4*>(&vs[r][j0]);
        float4 w1 = *reinterpret_cast<const float4*>(&vs[r][j0 + 4]);
        float4 w2 = *reinterpret_cast<const float4*>(&vs[r][j0 + 8]);
        float4 w3 = *reinterpret_cast<const float4*>(&vs[r][j0 + 12]);
        a0.x = fmaf(kv, w0.x, a0.x); a0.y = fmaf(kv, w0.y, a0.y);
        a0.z = fmaf(kv, w0.z, a0.z); a0.w = fmaf(kv, w0.w, a0.w);
        a1.x = fmaf(kv, w1.x, a1.x); a1.y = fmaf(kv, w1.y, a1.y);
        a1.z = fmaf(kv, w1.z, a1.z); a1.w = fmaf(kv, w1.w, a1.w);
        a2.x = fmaf(kv, w2.x, a2.x); a2.y = fmaf(kv, w2.y, a2.y);
        a2.z = fmaf(kv, w2.z, a2.z); a2.w = fmaf(kv, w2.w, a2.w);
        a3.x = fmaf(kv, w3.x, a3.x); a3.y = fmaf(kv, w3.y, a3.y);
        a3.z = fmaf(kv, w3.z, a3.z); a3.w = fmaf(kv, w3.w, a3.w);
    }
    float* dst = part + ((size_t)g * 32 + ch) * 4160;
    float* d0 = dst + i * 64 + j0;
    *reinterpret_cast<float4*>(d0)      = a0;
    *reinterpret_cast<float4*>(d0 + 4)  = a1;
    *reinterpret_cast<float4*>(d0 + 8)  = a2;
    *reinterpret_cast<float4*>(d0 + 12) = a3;
    if (tid < 64) {
        float ksum = 0.f;
#pragma unroll 8
        for (int r = 0; r < 64; ++r) ksum += ks[r][tid];
        dst[4096 + tid] = ksum;
    }
}

// ---------- stage2: sum 32 partials; KV -> bf16, Ksum -> f32 ----------
__global__ __launch_bounds__(256) void kv_reduce_k(
    const float* __restrict__ part, u16* __restrict__ KVh,
    float* __restrict__ Ksumf)
{
    const int g = blockIdx.x;
    const int e = blockIdx.y * 256 + threadIdx.x;
    if (e >= 4160) return;
    const float* p = part + (size_t)g * 32 * 4160 + e;
    float s = 0.f;
#pragma unroll 8
    for (int c = 0; c < 32; ++c) s += p[(size_t)c * 4160];
    if (e < 4096) KVh[g * 4096 + e] = f2bf(s);
    else          Ksumf[g * 64 + (e - 4096)] = s;
}

// ---------- KWT[b][o][h*64+i] = sum_j KV[i][j]*Wo[h*64+j][o], builtin bf16 --
__global__ __launch_bounds__(256, 2) void kw_gemm_k(
    const u16* __restrict__ WoT, const u16* __restrict__ KVb,
    u16* __restrict__ KWT)
{
    __shared__ __align__(16) u16 sA[128 * 64];
    __shared__ __align__(16) u16 sB[64 * 64];

    const int tid = threadIdx.x, lane = tid & 63, w = tid >> 6;
    const int o0 = blockIdx.x * 128;
    const int gh = blockIdx.y, b = gh >> 4, h = gh & 15, g = b * 4 + (h >> 2);
    const int fr = lane & 15, fq = lane >> 4;
    const int srow = lane >> 3, sslot = lane & 7;
    const int sswz = (sslot ^ srow) * 8;

#pragma unroll
    for (int c = 0; c < 4; ++c) {                      // A: 128 rows
        const int rb = w * 32 + c * 8;
        glds16(WoT + (size_t)(o0 + rb + srow) * 1024 + h * 64 + sswz, sA + rb * 64);
    }
#pragma unroll
    for (int c = 0; c < 2; ++c) {                      // B: 64 rows
        const int rb = w * 16 + c * 8;
        glds16(KVb + (size_t)g * 4096 + (rb + srow) * 64 + sswz, sB + rb * 64);
    }
    asm volatile("s_waitcnt vmcnt(0)" ::: "memory");
    __syncthreads();

    f32x4 acc[2][4] = {};
#pragma unroll
    for (int kk = 0; kk < 2; ++kk) {
        short8 a_h[2], b_h[4];
#pragma unroll
        for (int i = 0; i < 2; ++i) {
            const int row = w * 32 + i * 16 + fr;
            a_h[i] = *(const short8*)(sA + row * 64 + ((kk * 4 + fq) ^ (fr & 7)) * 8);
        }
#pragma unroll
        for (int j = 0; j < 4; ++j) {
            const int row = j * 16 + fr;
            b_h[j] = *(const short8*)(sB + row * 64 + ((kk * 4 + fq) ^ (fr & 7)) * 8);
        }
#pragma unroll
        for (int i = 0; i < 2; ++i)
#pragma unroll
            for (int j = 0; j < 4; ++j)
                acc[i][j] = __builtin_amdgcn_mfma_f32_16x16x32_bf16(
                    a_h[i], b_h[j], acc[i][j], 0, 0, 0);
    }
#pragma unroll
    for (int i = 0; i < 2; ++i)
#pragma unroll
        for (int j = 0; j < 4; ++j)
#pragma unroll
            for (int jj = 0; jj < 4; ++jj) {
                const int row = o0 + w * 32 + i * 16 + fq * 4 + jj;   // o
                const int col = j * 16 + fr;                          // i of KV
                KWT[((size_t)b * 1024 + row) * 1024 + h * 64 + col] =
                    f2bf(acc[i][j][jj]);
            }
}

// ---------- q_hat = q~ / max(q~.Ksum, 1e-6) : bf16 -> bf16 ----------
__global__ __launch_bounds__(256) void qhat_k(
    const u16* __restrict__ Qt, const float* __restrict__ Ksumf,
    u16* __restrict__ Qh)
{
    const int t = blockIdx.x * 256 + threadIdx.x;   // (m, h)
    const int m = t >> 4, h = t & 15;
    const int g = (m >> 11) * 4 + (h >> 2);
    const u16* q  = Qt + (size_t)m * 1024 + h * 64;
    const float* Ks = Ksumf + g * 64;

    float qv[64];
    float den = 0.f;
#pragma unroll
    for (int c = 0; c < 8; ++c) {
        short8 v8 = *reinterpret_cast<const short8*>(q + c * 8);
#pragma unroll
        for (int j = 0; j < 8; ++j) {
            qv[c * 8 + j] = bf2f((u16)v8[j]);
            den = fmaf(qv[c * 8 + j], Ks[c * 8 + j], den);
        }
    }
    const float rd = 1.f / fmaxf(den, 1e-6f);
    u16* o = Qh + (size_t)m * 1024 + h * 64;
#pragma unroll
    for (int c = 0; c < 8; ++c) {
        short8 ov;
#pragma unroll
        for (int j = 0; j < 8; ++j) ov[j] = (short)f2bf(qv[c * 8 + j] * rd);
        *reinterpret_cast<short8*>(o + c * 8) = ov;
    }
}

extern "C" void kernel_launch(void* const* d_in, const int* in_sizes, int n_in,
                              void* d_out, int out_size, void* d_ws, size_t ws_size,
                              hipStream_t stream)
{
    const float* x    = (const float*)d_in[0];
    const float* cosp = (const float*)d_in[1];
    const float* sinp = (const float*)d_in[2];
    const int*   msk  = (const int*)d_in[3];
    const float* Wq   = (const float*)d_in[4];
    const float* Wk   = (const float*)d_in[5];
    const float* Wv   = (const float*)d_in[6];
    const float* Wo   = (const float*)d_in[7];
    float* out = (float*)d_out;

    // ---- workspace layout (~46 MB) ----
    u16* xbf  = (u16*)d_ws;                           // [4096][1024]
    u16* wt   = xbf  + (size_t)M * K;                 // [1536][1024]
    u16* wot  = wt   + (size_t)1536 * K;              // [1024][1024] Wo^T
    u16* qt   = wot  + (size_t)K * K;                 // [4096][1024] q~ bf16
    u16* qhat = qt   + (size_t)M * K;                 // [4096][1024]
    u16* kvb  = qhat + (size_t)M * K;                 // [8][4096]
    u16* kwt  = kvb  + 8 * 4096;                      // [2][1024][1024]
    float* kvf   = (float*)(kwt + (size_t)2 * K * K); // [4096][512] k~|v f32
    float* part  = kvf + (size_t)M * 512;             // [8][32][4160]
    float* ksumf = part + (size_t)8 * 32 * 4160;      // [8][64]

    // 1) casts / transposes
    split_x_k<<<(M * K) / 1024, 256, 0, stream>>>(x, xbf);
    dim3 wb(32, 8);
    wsplit_k<<<dim3(32, 32), wb, 0, stream>>>(Wq, 1024, wt, 0);
    wsplit_k<<<dim3(8, 32),  wb, 0, stream>>>(Wk, 256,  wt, 1024);
    wsplit_k<<<dim3(8, 32),  wb, 0, stream>>>(Wv, 256,  wt, 1280);
    wsplit_k<<<dim3(32, 32), wb, 0, stream>>>(Wo, 1024, wot, 0);

    // 2) QKV projection + fused rope/phi/mask epilogue (q->bf16, k|v->f32)
    gemm_k<0><<<dim3(M / 128, 1536 / 128, 1), 256, 0, stream>>>(
        xbf, wt, qt, kvf, nullptr, 0, 0, 0, 0, cosp, sinp, msk);

    // 3) KV & Ksum (atomic-free two-stage)
    kv_stage1_k<<<dim3(8, 32), 256, 0, stream>>>(kvf, part);
    kv_reduce_k<<<dim3(8, 17), 256, 0, stream>>>(part, kvb, ksumf);

    // 4) KWT[b] = per-head KV @ Wo slices
    kw_gemm_k<<<dim3(8, 32), 256, 0, stream>>>(wot, kvb, kwt);

    // 5) q_hat = q~ / den
    qhat_k<<<(M * 16) / 256, 256, 0, stream>>>(qt, ksumf, qhat);

    // 6) out_b = q_hat_b @ KWT_b^T
    gemm_k<1><<<dim3(2048 / 128, HID / 128, 2), 256, 0, stream>>>(
        qhat, kwt, nullptr, nullptr, out, HID, 2048, 1024, 2048,
        nullptr, nullptr, nullptr);
}

// Round 9
// 69.767 us; speedup vs baseline: 5.8409x; 1.2194x over previous
//
#include <hip/hip_runtime.h>
#include <hip/hip_bf16.h>

using u16 = unsigned short;
using u32 = unsigned int;

namespace {
constexpr int S   = 2048;
constexpr int HID = 1024;
constexpr int M   = 4096;                  // B*S
constexpr int K   = 1024;                  // inner dim of both big GEMMs
}

typedef __attribute__((ext_vector_type(8))) short short8;   // 8 bf16 = 4 VGPR
typedef __attribute__((ext_vector_type(4))) float f32x4;

__device__ __forceinline__ u16 f2bf(float f) {
    u32 u = __builtin_bit_cast(u32, f);
    u += 0x7fffu + ((u >> 16) & 1u);       // RNE
    return (u16)(u >> 16);
}
__device__ __forceinline__ float bf2f(u16 h) {
    return __builtin_bit_cast(float, (u32)h << 16);
}
__device__ __forceinline__ float phi(float x) {   // elu(x)+1
    return x > 0.f ? x + 1.f : __expf(x);
}
__device__ __forceinline__ void glds16(const u16* g, u16* l) {
    __builtin_amdgcn_global_load_lds(
        (const __attribute__((address_space(1))) u32*)g,
        (__attribute__((address_space(3))) u32*)l, 16, 0, 0);
}

// ---- single-bf16 MFMA GEMM, 64x128 tile, BK=64, double-buffered LDS -------
// 4 waves as 2x2: wave rows wm*32..+32, cols wn*64..+64.
// LDS rows are 64 u16 = 128 B; k-slot XOR swizzle (slot^row&7) both sides.
// MODE 0: QKV projection. Epilogue: q tiles (n0<1024) -> rope+phi -> bf16 Cq;
//         k tiles -> rope+phi*mask -> f32 Ckv[.][0..255]; v -> Ckv[.][256..511].
// MODE 1: plain f32 C write, z-batched via zAr/zCr row offsets.
template <int MODE>
__global__ __launch_bounds__(256, 3) void gemm_k(
    const u16* __restrict__ A, const u16* __restrict__ B,
    u16* __restrict__ Cq, float* __restrict__ Ckv,
    float* __restrict__ Cf, int ldc, int zAr, int zBr, int zCr,
    const float* __restrict__ Cos, const float* __restrict__ Sin,
    const int* __restrict__ Mask)
{
    constexpr int BK = 64;
    constexpr int NT = K / BK;                     // 16 K-tiles
    __shared__ __align__(16) u16 sA0[64 * BK],  sA1[64 * BK];    // 8 KB each
    __shared__ __align__(16) u16 sB0[128 * BK], sB1[128 * BK];   // 16 KB each

    A += (size_t)blockIdx.z * zAr * K;
    B += (size_t)blockIdx.z * zBr * K;
    if (MODE == 1) Cf += (size_t)blockIdx.z * zCr * ldc;

    const int tid  = threadIdx.x;
    const int lane = tid & 63, w = tid >> 6;
    const int wm = w & 1, wn = w >> 1;             // 2x2 wave grid
    const int m0 = blockIdx.x * 64, n0 = blockIdx.y * 128;
    const int fr = lane & 15, fq = lane >> 4;

    const int srow  = lane >> 3;                   // 0..7 staging row in chunk
    const int sslot = lane & 7;                    // LDS k-slot this lane fills
    const int sswz  = (sslot ^ srow) * 8;          // swizzled global k-elem

    // per-thread global bases (chunk 0); chunk c adds c*32 rows
    const u16* Asrc = A + (size_t)(m0 + w * 8 + srow) * K + sswz;
    const u16* Bsrc = B + (size_t)(n0 + w * 8 + srow) * K + sswz;
    const int ldsb = (w * 8) * BK;                 // wave-uniform LDS base

    f32x4 acc[2][4] = {};

#define STAGE(dA, dB, kt)                                          \
    do {                                                           \
        glds16(Asrc + (kt),                 dA + ldsb);            \
        glds16(Asrc + (size_t)32 * K + (kt), dA + 32 * BK + ldsb); \
        glds16(Bsrc + (kt),                 dB + ldsb);            \
        glds16(Bsrc + (size_t)32 * K + (kt), dB + 32 * BK + ldsb); \
        glds16(Bsrc + (size_t)64 * K + (kt), dB + 64 * BK + ldsb); \
        glds16(Bsrc + (size_t)96 * K + (kt), dB + 96 * BK + ldsb); \
    } while (0)

#define COMPUTE(sAc, sBc)                                                    \
    do {                                                                     \
        _Pragma("unroll")                                                    \
        for (int kk = 0; kk < 2; ++kk) {                                     \
            const int ks = ((kk * 4 + fq) ^ (fr & 7)) * 8;                   \
            short8 ah[2], bh[4];                                             \
            _Pragma("unroll")                                                \
            for (int i = 0; i < 2; ++i)                                      \
                ah[i] = *(const short8*)(sAc + (wm * 32 + i * 16 + fr) * BK + ks); \
            _Pragma("unroll")                                                \
            for (int j = 0; j < 4; ++j)                                      \
                bh[j] = *(const short8*)(sBc + (wn * 64 + j * 16 + fr) * BK + ks); \
            _Pragma("unroll")                                                \
            for (int i = 0; i < 2; ++i)                                      \
                _Pragma("unroll")                                            \
                for (int j = 0; j < 4; ++j)                                  \
                    acc[i][j] = __builtin_amdgcn_mfma_f32_16x16x32_bf16(     \
                        ah[i], bh[j], acc[i][j], 0, 0, 0);                   \
        }                                                                    \
    } while (0)

#define SYNC()                                              \
    do {                                                    \
        asm volatile("s_waitcnt vmcnt(0)" ::: "memory");    \
        __syncthreads();                                    \
    } while (0)

    STAGE(sA0, sB0, 0);
    SYNC();
#pragma unroll 1
    for (int t = 0; t < NT; t += 2) {
        if (t + 1 < NT) STAGE(sA1, sB1, (t + 1) * BK);     // prefetch t+1
        COMPUTE(sA0, sB0);                                  // compute t
        SYNC();
        if (t + 2 < NT) STAGE(sA0, sB0, (t + 2) * BK);     // prefetch t+2
        COMPUTE(sA1, sB1);                                  // compute t+1
        SYNC();
    }
#undef STAGE
#undef COMPUTE
#undef SYNC

    const bool isQ = (MODE == 0) && (n0 < 1024);
    const bool isK = (MODE == 0) && (n0 >= 1024) && (n0 < 1280);
#pragma unroll
    for (int i = 0; i < 2; ++i)
#pragma unroll
        for (int jj = 0; jj < 4; ++jj) {
            const int row = m0 + wm * 32 + i * 16 + fq * 4 + jj;
            float v0 = acc[i][0][jj], v1 = acc[i][1][jj];
            float v2 = acc[i][2][jj], v3 = acc[i][3][jj];
            if (MODE == 1) {
                float* cr = &Cf[(size_t)row * ldc + n0 + wn * 64 + fr];
                cr[0] = v0; cr[16] = v1; cr[32] = v2; cr[48] = v3;
                continue;
            }
            if (isQ || isK) {                      // rope + phi (head-aligned)
                const int sb = (row & (S - 1)) * 64;
                // pairs (d, d+32): (v0@fr, v2@fr+32), (v1@16+fr, v3@48+fr)
                float r0 = v0 * Cos[sb + fr]      - v2 * Sin[sb + fr];
                float r2 = v2 * Cos[sb + fr + 32] + v0 * Sin[sb + fr + 32];
                float r1 = v1 * Cos[sb + fr + 16] - v3 * Sin[sb + fr + 16];
                float r3 = v3 * Cos[sb + fr + 48] + v1 * Sin[sb + fr + 48];
                v0 = phi(r0); v1 = phi(r1); v2 = phi(r2); v3 = phi(r3);
            }
            if (isQ) {
                u16* cr = &Cq[(size_t)row * 1024 + n0 + wn * 64 + fr];
                cr[0]  = f2bf(v0); cr[16] = f2bf(v1);
                cr[32] = f2bf(v2); cr[48] = f2bf(v3);
            } else if (isK) {
                const float mv = (float)Mask[row];
                float* cr = &Ckv[(size_t)row * 512 + (n0 - 1024) + wn * 64 + fr];
                cr[0] = v0 * mv; cr[16] = v1 * mv;
                cr[32] = v2 * mv; cr[48] = v3 * mv;
            } else {                               // v passthrough
                float* cr = &Ckv[(size_t)row * 512 + 256 + (n0 - 1280) + wn * 64 + fr];
                cr[0] = v0; cr[16] = v1; cr[32] = v2; cr[48] = v3;
            }
        }
}

// ---------- fused preprocessing: x->bf16 + 4 weight transposes, 1 launch ----
// bid < 4096: split_x (float4/thread). Else weight transpose jobs.
__global__ __launch_bounds__(256) void prep_k(
    const float* __restrict__ X,  u16* __restrict__ Xb,
    const float* __restrict__ Wq, const float* __restrict__ Wk,
    const float* __restrict__ Wv, const float* __restrict__ Wo,
    u16* __restrict__ wt, u16* __restrict__ wot)
{
    const int bid = blockIdx.x, tid = threadIdx.x;
    if (bid < 4096) {
        const int i = (bid * 256 + tid) * 4;
        float4 v = *reinterpret_cast<const float4*>(&X[i]);
        ushort4 h;
        h.x = f2bf(v.x); h.y = f2bf(v.y); h.z = f2bf(v.z); h.w = f2bf(v.w);
        *reinterpret_cast<ushort4*>(&Xb[i]) = h;
        return;
    }
    int r = bid - 4096;
    const float* W; u16* T; int N, nbase, bx, by;
    if (r < 1024)      { W = Wq; T = wt;  N = 1024; nbase = 0;    bx = r & 31; by = r >> 5; }
    else if (r < 1280) { r -= 1024; W = Wk; T = wt; N = 256; nbase = 1024; bx = r & 7; by = r >> 3; }
    else if (r < 1536) { r -= 1280; W = Wv; T = wt; N = 256; nbase = 1280; bx = r & 7; by = r >> 3; }
    else               { r -= 1536; W = Wo; T = wot; N = 1024; nbase = 0;  bx = r & 31; by = r >> 5; }

    __shared__ float t[32][33];
    const int n0 = bx * 32, k0 = by * 32;
    const int tx = tid & 31, ty = tid >> 5;        // 32 x 8
#pragma unroll
    for (int i = 0; i < 4; ++i)
        t[ty + i * 8][tx] = W[(size_t)(k0 + ty + i * 8) * N + n0 + tx];
    __syncthreads();
#pragma unroll
    for (int i = 0; i < 4; ++i) {
        const int n = ty + i * 8;
        T[(size_t)(nbase + n0 + n) * 1024 + k0 + tx] = f2bf(t[tx][n]);
    }
}

// ---------- stage1: per (group, 64-row chunk) partial KV + Ksum -------------
__global__ __launch_bounds__(256) void kv_stage1_k(
    const float* __restrict__ KVf, float* __restrict__ part)
{
    const int g  = blockIdx.x;             // b*4 + kvh
    const int ch = blockIdx.y;             // 32 chunks of 64 rows
    const int b  = g >> 2, kvh = g & 3;
    const int tid = threadIdx.x;

    __shared__ float ks[64][64];
    __shared__ float vs[64][64];
    const int m0 = b * S + ch * 64;
#pragma unroll
    for (int l = 0; l < 4; ++l) {
        int idx = tid + l * 256;           // 0..1023
        int r = idx >> 4, q4 = (idx & 15) * 4;
        const float* src = KVf + (size_t)(m0 + r) * 512 + kvh * 64;
        *reinterpret_cast<float4*>(&ks[r][q4]) = *reinterpret_cast<const float4*>(src + q4);
        *reinterpret_cast<float4*>(&vs[r][q4]) = *reinterpret_cast<const float4*>(src + 256 + q4);
    }
    __syncthreads();

    const int i = tid >> 2, j0 = (tid & 3) * 16;
    float4 a0 = {0,0,0,0}, a1 = {0,0,0,0}, a2 = {0,0,0,0}, a3 = {0,0,0,0};
#pragma unroll 8
    for (int r = 0; r < 64; ++r) {
        float kv = ks[r][i];
        float4 w0 = *reinterpret_cast<const float4*>(&vs[r][j0]);
        float4 w1 = *reinterpret_cast<const float4*>(&vs[r][j0 + 4]);
        float4 w2 = *reinterpret_cast<const float4*>(&vs[r][j0 + 8]);
        float4 w3 = *reinterpret_cast<const float4*>(&vs[r][j0 + 12]);
        a0.x = fmaf(kv, w0.x, a0.x); a0.y = fmaf(kv, w0.y, a0.y);
        a0.z = fmaf(kv, w0.z, a0.z); a0.w = fmaf(kv, w0.w, a0.w);
        a1.x = fmaf(kv, w1.x, a1.x); a1.y = fmaf(kv, w1.y, a1.y);
        a1.z = fmaf(kv, w1.z, a1.z); a1.w = fmaf(kv, w1.w, a1.w);
        a2.x = fmaf(kv, w2.x, a2.x); a2.y = fmaf(kv, w2.y, a2.y);
        a2.z = fmaf(kv, w2.z, a2.z); a2.w = fmaf(kv, w2.w, a2.w);
        a3.x = fmaf(kv, w3.x, a3.x); a3.y = fmaf(kv, w3.y, a3.y);
        a3.z = fmaf(kv, w3.z, a3.z); a3.w = fmaf(kv, w3.w, a3.w);
    }
    float* dst = part + ((size_t)g * 32 + ch) * 4160;
    float* d0 = dst + i * 64 + j0;
    *reinterpret_cast<float4*>(d0)      = a0;
    *reinterpret_cast<float4*>(d0 + 4)  = a1;
    *reinterpret_cast<float4*>(d0 + 8)  = a2;
    *reinterpret_cast<float4*>(d0 + 12) = a3;
    if (tid < 64) {
        float ksum = 0.f;
#pragma unroll 8
        for (int r = 0; r < 64; ++r) ksum += ks[r][tid];
        dst[4096 + tid] = ksum;
    }
}

// ---------- stage2: sum 32 partials; KV -> bf16, Ksum -> f32 ----------
__global__ __launch_bounds__(256) void kv_reduce_k(
    const float* __restrict__ part, u16* __restrict__ KVh,
    float* __restrict__ Ksumf)
{
    const int g = blockIdx.x;
    const int e = blockIdx.y * 256 + threadIdx.x;
    if (e >= 4160) return;
    const float* p = part + (size_t)g * 32 * 4160 + e;
    float s = 0.f;
#pragma unroll 8
    for (int c = 0; c < 32; ++c) s += p[(size_t)c * 4160];
    if (e < 4096) KVh[g * 4096 + e] = f2bf(s);
    else          Ksumf[g * 64 + (e - 4096)] = s;
}

// ---------- KWT[b][o][h*64+i] = sum_j KV[i][j]*Wo[h*64+j][o], builtin bf16 --
__global__ __launch_bounds__(256, 2) void kw_gemm_k(
    const u16* __restrict__ WoT, const u16* __restrict__ KVb,
    u16* __restrict__ KWT)
{
    __shared__ __align__(16) u16 sA[128 * 64];
    __shared__ __align__(16) u16 sB[64 * 64];

    const int tid = threadIdx.x, lane = tid & 63, w = tid >> 6;
    const int o0 = blockIdx.x * 128;
    const int gh = blockIdx.y, b = gh >> 4, h = gh & 15, g = b * 4 + (h >> 2);
    const int fr = lane & 15, fq = lane >> 4;
    const int srow = lane >> 3, sslot = lane & 7;
    const int sswz = (sslot ^ srow) * 8;

#pragma unroll
    for (int c = 0; c < 4; ++c) {                      // A: 128 rows
        const int rb = w * 32 + c * 8;
        glds16(WoT + (size_t)(o0 + rb + srow) * 1024 + h * 64 + sswz, sA + rb * 64);
    }
#pragma unroll
    for (int c = 0; c < 2; ++c) {                      // B: 64 rows
        const int rb = w * 16 + c * 8;
        glds16(KVb + (size_t)g * 4096 + (rb + srow) * 64 + sswz, sB + rb * 64);
    }
    asm volatile("s_waitcnt vmcnt(0)" ::: "memory");
    __syncthreads();

    f32x4 acc[2][4] = {};
#pragma unroll
    for (int kk = 0; kk < 2; ++kk) {
        short8 a_h[2], b_h[4];
#pragma unroll
        for (int i = 0; i < 2; ++i) {
            const int row = w * 32 + i * 16 + fr;
            a_h[i] = *(const short8*)(sA + row * 64 + ((kk * 4 + fq) ^ (fr & 7)) * 8);
        }
#pragma unroll
        for (int j = 0; j < 4; ++j) {
            const int row = j * 16 + fr;
            b_h[j] = *(const short8*)(sB + row * 64 + ((kk * 4 + fq) ^ (fr & 7)) * 8);
        }
#pragma unroll
        for (int i = 0; i < 2; ++i)
#pragma unroll
            for (int j = 0; j < 4; ++j)
                acc[i][j] = __builtin_amdgcn_mfma_f32_16x16x32_bf16(
                    a_h[i], b_h[j], acc[i][j], 0, 0, 0);
    }
#pragma unroll
    for (int i = 0; i < 2; ++i)
#pragma unroll
        for (int j = 0; j < 4; ++j)
#pragma unroll
            for (int jj = 0; jj < 4; ++jj) {
                const int row = o0 + w * 32 + i * 16 + fq * 4 + jj;   // o
                const int col = j * 16 + fr;                          // i of KV
                KWT[((size_t)b * 1024 + row) * 1024 + h * 64 + col] =
                    f2bf(acc[i][j][jj]);
            }
}

// ---------- q_hat = q~ / max(q~.Ksum, 1e-6) : bf16 -> bf16 ----------
__global__ __launch_bounds__(256) void qhat_k(
    const u16* __restrict__ Qt, const float* __restrict__ Ksumf,
    u16* __restrict__ Qh)
{
    const int t = blockIdx.x * 256 + threadIdx.x;   // (m, h)
    const int m = t >> 4, h = t & 15;
    const int g = (m >> 11) * 4 + (h >> 2);
    const u16* q  = Qt + (size_t)m * 1024 + h * 64;
    const float* Ks = Ksumf + g * 64;

    float qv[64];
    float den = 0.f;
#pragma unroll
    for (int c = 0; c < 8; ++c) {
        short8 v8 = *reinterpret_cast<const short8*>(q + c * 8);
#pragma unroll
        for (int j = 0; j < 8; ++j) {
            qv[c * 8 + j] = bf2f((u16)v8[j]);
            den = fmaf(qv[c * 8 + j], Ks[c * 8 + j], den);
        }
    }
    const float rd = 1.f / fmaxf(den, 1e-6f);
    u16* o = Qh + (size_t)m * 1024 + h * 64;
#pragma unroll
    for (int c = 0; c < 8; ++c) {
        short8 ov;
#pragma unroll
        for (int j = 0; j < 8; ++j) ov[j] = (short)f2bf(qv[c * 8 + j] * rd);
        *reinterpret_cast<short8*>(o + c * 8) = ov;
    }
}

extern "C" void kernel_launch(void* const* d_in, const int* in_sizes, int n_in,
                              void* d_out, int out_size, void* d_ws, size_t ws_size,
                              hipStream_t stream)
{
    const float* x    = (const float*)d_in[0];
    const float* cosp = (const float*)d_in[1];
    const float* sinp = (const float*)d_in[2];
    const int*   msk  = (const int*)d_in[3];
    const float* Wq   = (const float*)d_in[4];
    const float* Wk   = (const float*)d_in[5];
    const float* Wv   = (const float*)d_in[6];
    const float* Wo   = (const float*)d_in[7];
    float* out = (float*)d_out;

    // ---- workspace layout (~46 MB) ----
    u16* xbf  = (u16*)d_ws;                           // [4096][1024]
    u16* wt   = xbf  + (size_t)M * K;                 // [1536][1024]
    u16* wot  = wt   + (size_t)1536 * K;              // [1024][1024] Wo^T
    u16* qt   = wot  + (size_t)K * K;                 // [4096][1024] q~ bf16
    u16* qhat = qt   + (size_t)M * K;                 // [4096][1024]
    u16* kvb  = qhat + (size_t)M * K;                 // [8][4096]
    u16* kwt  = kvb  + 8 * 4096;                      // [2][1024][1024]
    float* kvf   = (float*)(kwt + (size_t)2 * K * K); // [4096][512] k~|v f32
    float* part  = kvf + (size_t)M * 512;             // [8][32][4160]
    float* ksumf = part + (size_t)8 * 32 * 4160;      // [8][64]

    // 1) fused casts/transposes (one launch)
    prep_k<<<4096 + 1024 + 256 + 256 + 1024, 256, 0, stream>>>(
        x, xbf, Wq, Wk, Wv, Wo, wt, wot);

    // 2) QKV projection + fused rope/phi/mask epilogue (q->bf16, k|v->f32)
    gemm_k<0><<<dim3(M / 64, 1536 / 128, 1), 256, 0, stream>>>(
        xbf, wt, qt, kvf, nullptr, 0, 0, 0, 0, cosp, sinp, msk);

    // 3) KV & Ksum (atomic-free two-stage)
    kv_stage1_k<<<dim3(8, 32), 256, 0, stream>>>(kvf, part);
    kv_reduce_k<<<dim3(8, 17), 256, 0, stream>>>(part, kvb, ksumf);

    // 4) KWT[b] = per-head KV @ Wo slices
    kw_gemm_k<<<dim3(8, 32), 256, 0, stream>>>(wot, kvb, kwt);

    // 5) q_hat = q~ / den
    qhat_k<<<(M * 16) / 256, 256, 0, stream>>>(qt, ksumf, qhat);

    // 6) out_b = q_hat_b @ KWT_b^T
    gemm_k<1><<<dim3(2048 / 64, HID / 128, 2), 256, 0, stream>>>(
        qhat, kwt, nullptr, nullptr, out, HID, 2048, 1024, 2048,
        nullptr, nullptr, nullptr);
}